// Round 1
// baseline (246.422 us; speedup 1.0000x reference)
//
#include <hip/hip_runtime.h>
#include <stdint.h>

typedef __bf16 bf16x8 __attribute__((ext_vector_type(8)));
typedef short s16x8 __attribute__((ext_vector_type(8)));
typedef float f32x4 __attribute__((ext_vector_type(4)));
typedef unsigned long long ull;

#define BB 16384
#define KD 784
#define KP 800
#define N1 1024
#define N2 10
#define NTOT (BB * N2)  // 163840

// ---- workspace layout (bytes), total ~79.1 MB ----
#define OFF_AQ 0ULL
#define SZ_AQ (26214400ULL)  // 16384*800*2  bf16
#define OFF_W1Q (OFF_AQ + SZ_AQ)
#define SZ_W1Q (1638400ULL)  // 1024*800*2  bf16
#define OFF_W2Q (OFF_W1Q + SZ_W1Q)
#define SZ_W2Q (16384ULL)  // 10*1024 i8 (padded)
#define OFF_C1 (OFF_W2Q + SZ_W2Q)
#define SZ_C1 (33554432ULL)  // 16384*1024 i16
#define OFF_T8 (OFF_C1 + SZ_C1)
#define SZ_T8 (16777216ULL)  // 16384*1024 i8
#define OFF_STATS (OFF_T8 + SZ_T8)
#define SZ_STATS (16384ULL)
// stats sublayout: colsum int[1024] @0; colsq ull[1024] @4096; sum2 int[16] @12288;
//                  sq2 ull[16] @12352; gsum int @12480; gsq int @12484
#define OFF_BN1 (OFF_STATS + SZ_STATS)
#define SZ_BN1 (16384ULL)  // dmean double[1024] + dinv double[1024]
#define OFF_C2 (OFF_BN1 + SZ_BN1)
#define SZ_C2 (655360ULL)  // 16384*10 int
#define OFF_T2 (OFF_C2 + SZ_C2)
#define SZ_T2 (163840ULL)  // i8

__device__ __forceinline__ void async16(const void* g, void* l) {
  __builtin_amdgcn_global_load_lds((__attribute__((address_space(1))) void*)(void*)(g),
                                   (__attribute__((address_space(3))) void*)(l), 16, 0, 0);
}

// K0: quantize x -> Aq (bf16, K padded to 800), W1 -> W1q (bf16 padded), W2 -> W2q (i8)
__global__ void k0_quant(const float* __restrict__ x, const float* __restrict__ W1,
                         const float* __restrict__ W2, uint16_t* __restrict__ Aq,
                         uint16_t* __restrict__ W1q, int8_t* __restrict__ W2q) {
  int idx = blockIdx.x * 256 + threadIdx.x;
  const int NA = BB * KP;   // 13107200
  const int NW = N1 * KP;   // 819200
  if (idx < NA) {
    int r = idx / KP, k = idx - r * KP;
    uint16_t o = 0;
    if (k < KD) {
      float q = rintf(2.0f * x[r * KD + k] - 1.0f);
      o = (q > 0.5f) ? 0x3F80u : ((q < -0.5f) ? 0xBF80u : 0u);
    }
    Aq[idx] = o;
  } else if (idx < NA + NW) {
    int j = idx - NA;
    int r = j / KP, k = j - r * KP;
    uint16_t o = 0;
    if (k < KD) {
      float q = rintf(W1[r * KD + k]);
      o = (q > 0.5f) ? 0x3F80u : ((q < -0.5f) ? 0xBF80u : 0u);
    }
    W1q[j] = o;
  } else if (idx < NA + NW + N2 * N1) {
    int j = idx - NA - NW;
    float q = rintf(W2[j]);
    W2q[j] = (q > 0.5f) ? 1 : ((q < -0.5f) ? -1 : 0);
  }
}

// K1: C1 = Aq @ W1q^T  (m97-style 128x128 tile, bf16 MFMA, exact integer result -> i16)
__global__ __launch_bounds__(256, 2) void k1_gemm1(const uint16_t* __restrict__ Aq,
                                                   const uint16_t* __restrict__ W1q,
                                                   short* __restrict__ C1) {
  __shared__ uint16_t As[128 * 32];
  __shared__ uint16_t Bs[128 * 32];
  const int t = threadIdx.x;
  const int lane = t & 63, wave = t >> 6;
  const int wr = wave >> 1, wc = wave & 1;
  const int rowBase = blockIdx.y * 128, colBase = blockIdx.x * 128;

  f32x4 acc[4][4] = {};

  const int ar0 = t >> 2, ak0 = (t & 3) * 8;
  const int ar1 = (t + 256) >> 2, ak1 = ((t + 256) & 3) * 8;

  for (int kt = 0; kt < KP / 32; ++kt) {
    __syncthreads();
    const int kb = kt * 32;
    async16(&Aq[(size_t)(rowBase + ar0) * KP + kb + ak0], &As[ar0 * 32 + ak0]);
    async16(&Aq[(size_t)(rowBase + ar1) * KP + kb + ak1], &As[ar1 * 32 + ak1]);
    async16(&W1q[(size_t)(colBase + ar0) * KP + kb + ak0], &Bs[ar0 * 32 + ak0]);
    async16(&W1q[(size_t)(colBase + ar1) * KP + kb + ak1], &Bs[ar1 * 32 + ak1]);
    __syncthreads();
    const int m = lane & 15, q8 = (lane >> 4) * 8;
    s16x8 av[4], bv[4];
#pragma unroll
    for (int i = 0; i < 4; ++i) av[i] = *(const s16x8*)&As[(64 * wr + 16 * i + m) * 32 + q8];
#pragma unroll
    for (int j = 0; j < 4; ++j) bv[j] = *(const s16x8*)&Bs[(64 * wc + 16 * j + m) * 32 + q8];
#pragma unroll
    for (int i = 0; i < 4; ++i)
#pragma unroll
      for (int j = 0; j < 4; ++j)
        acc[i][j] = __builtin_amdgcn_mfma_f32_16x16x32_bf16(
            __builtin_bit_cast(bf16x8, av[i]), __builtin_bit_cast(bf16x8, bv[j]), acc[i][j], 0,
            0, 0);
  }
  const int q = lane >> 4, cl = lane & 15;
#pragma unroll
  for (int i = 0; i < 4; ++i)
#pragma unroll
    for (int j = 0; j < 4; ++j)
#pragma unroll
      for (int rg = 0; rg < 4; ++rg) {
        int row = rowBase + 64 * wr + 16 * i + q * 4 + rg;
        int col = colBase + 64 * wc + 16 * j + cl;
        C1[(size_t)row * N1 + col] = (short)acc[i][j][rg];
      }
}

// K2: exact per-column sum / sumsq of C1 (int / int64 atomics)
__global__ void k2_stats1(const short* __restrict__ C1, int* __restrict__ colsum,
                          ull* __restrict__ colsq) {
  int c = blockIdx.x * 256 + threadIdx.x;  // gridDim.x = 4
  int r0 = blockIdx.y * 256;               // gridDim.y = 64
  int s = 0, sqi = 0;                      // sqi <= 256*784^2 = 1.57e8, fits int32
  for (int r = 0; r < 256; ++r) {
    int v = C1[(size_t)(r0 + r) * N1 + c];
    s += v;
    sqi += v * v;
  }
  atomicAdd(&colsum[c], s);
  atomicAdd(&colsq[c], (ull)sqi);
}

// K3: BN1 constants in double (exact-integer inputs)
__global__ void k3_bn1(const int* __restrict__ colsum, const ull* __restrict__ colsq,
                       double* __restrict__ dmean, double* __restrict__ dinv) {
  int c = threadIdx.x;  // 1024 threads, 1 block
  double mean = (double)colsum[c] / 16384.0;
  double var = (double)colsq[c] / 16384.0 - mean * mean;
  dmean[c] = mean;
  dinv[c] = 1.0 / sqrt(var + 1e-5);
}

// K4: t8 = ternary(batchnorm(C1))  (double precision decision, exact-int input)
__global__ void k4_bnq(const short* __restrict__ C1, const double* __restrict__ dmean,
                       const double* __restrict__ dinv, const float* __restrict__ g1,
                       const float* __restrict__ b1, int8_t* __restrict__ t8) {
  int id = blockIdx.x * 256 + threadIdx.x;  // 4,194,304 threads, 4 elems each
  int base = id * 4;
  short4 v = *(const short4*)&C1[base];
  int c0 = base & (N1 - 1);
  short vv[4] = {v.x, v.y, v.z, v.w};
  int8_t o[4];
#pragma unroll
  for (int u = 0; u < 4; ++u) {
    int c = c0 + u;
    double z = ((double)vv[u] - dmean[c]) * dinv[c] * (double)g1[c] + (double)b1[c];
    double qq = rint(z);
    qq = qq < -1.0 ? -1.0 : (qq > 1.0 ? 1.0 : qq);
    o[u] = (int8_t)qq;
  }
  *(char4*)&t8[base] = make_char4(o[0], o[1], o[2], o[3]);
}

// K5: C2 = t8 @ W2q^T (wave-per-row, register-resident W2) + exact col stats
__global__ __launch_bounds__(256) void k5_gemm2(const int8_t* __restrict__ t8,
                                                const int8_t* __restrict__ W2q,
                                                int* __restrict__ C2, int* __restrict__ sum2,
                                                ull* __restrict__ sq2) {
  __shared__ int ls[N2];
  __shared__ ull lq[N2];
  int t = threadIdx.x;
  if (t < N2) {
    ls[t] = 0;
    lq[t] = 0;
  }
  __syncthreads();
  int lane = t & 63, wave = t >> 6;
  int4 w2r[N2];
#pragma unroll
  for (int c = 0; c < N2; ++c) w2r[c] = *(const int4*)&W2q[c * N1 + lane * 16];
  int gw = blockIdx.x * 4 + wave;
  for (int r = gw; r < BB; r += gridDim.x * 4) {
    int4 a = *(const int4*)&t8[(size_t)r * N1 + lane * 16];
    const int8_t* ap = (const int8_t*)&a;
    int s[N2];
#pragma unroll
    for (int c = 0; c < N2; ++c) {
      const int8_t* wp = (const int8_t*)&w2r[c];
      int acc = 0;
#pragma unroll
      for (int j = 0; j < 16; ++j) acc += (int)ap[j] * (int)wp[j];
      s[c] = acc;
    }
#pragma unroll
    for (int c = 0; c < N2; ++c) {
#pragma unroll
      for (int off = 32; off > 0; off >>= 1) s[c] += __shfl_xor(s[c], off, 64);
    }
    if (lane == 0) {
#pragma unroll
      for (int c = 0; c < N2; ++c) {
        C2[r * N2 + c] = s[c];
        atomicAdd(&ls[c], s[c]);
        atomicAdd(&lq[c], (ull)((long long)s[c] * s[c]));
      }
    }
  }
  __syncthreads();
  if (t < N2) {
    atomicAdd(&sum2[t], ls[t]);
    atomicAdd(&sq2[t], lq[t]);
  }
}

// K7: t2 = ternary(batchnorm2(C2)) + global sum/sumsq of t2 (exact int)
__global__ void k7_bn2q(const int* __restrict__ C2, const int* __restrict__ sum2,
                        const ull* __restrict__ sq2, const float* __restrict__ g2,
                        const float* __restrict__ b2, int8_t* __restrict__ t2,
                        int* __restrict__ gsum, int* __restrict__ gsq) {
  int id = blockIdx.x * 256 + threadIdx.x;  // 163840 total
  int c = id % N2;
  int v = C2[id];
  double mean = (double)sum2[c] / 16384.0;
  double var = (double)sq2[c] / 16384.0 - mean * mean;
  double z = ((double)v - mean) / sqrt(var + 1e-5) * (double)g2[c] + (double)b2[c];
  double qq = rint(z);
  qq = qq < -1.0 ? -1.0 : (qq > 1.0 ? 1.0 : qq);
  int ti = (int)qq;
  t2[id] = (int8_t)ti;
  int s = ti, sq = ti * ti;
#pragma unroll
  for (int off = 32; off > 0; off >>= 1) {
    s += __shfl_xor(s, off, 64);
    sq += __shfl_xor(sq, off, 64);
  }
  __shared__ int bs, bq;
  if (threadIdx.x == 0) {
    bs = 0;
    bq = 0;
  }
  __syncthreads();
  if ((threadIdx.x & 63) == 0) {
    atomicAdd(&bs, s);
    atomicAdd(&bq, sq);
  }
  __syncthreads();
  if (threadIdx.x == 0) {
    atomicAdd(gsum, bs);
    atomicAdd(gsq, bq);
  }
}

// K9: out = tensornorm(t2)  (unbiased var, eps=1e-4)
__global__ void k9_out(const int8_t* __restrict__ t2, const int* __restrict__ gsum,
                       const int* __restrict__ gsq, const float* __restrict__ tn_w,
                       const float* __restrict__ tn_b, float* __restrict__ out) {
  int id = blockIdx.x * 256 + threadIdx.x;
  double n = (double)NTOT;
  double sm = (double)*gsum;
  double mean = sm / n;
  double var = ((double)*gsq - sm * sm / n) / (n - 1.0);
  double alpha = (double)tn_w[0] / sqrt(var + 1e-4);
  out[id] = (float)(((double)t2[id] - mean) * alpha + (double)tn_b[0]);
}

extern "C" void kernel_launch(void* const* d_in, const int* in_sizes, int n_in, void* d_out,
                              int out_size, void* d_ws, size_t ws_size, hipStream_t stream) {
  const float* x = (const float*)d_in[0];
  const float* W1 = (const float*)d_in[1];
  const float* g1 = (const float*)d_in[2];
  const float* b1 = (const float*)d_in[3];
  const float* W2 = (const float*)d_in[4];
  const float* g2 = (const float*)d_in[5];
  const float* b2 = (const float*)d_in[6];
  const float* tnw = (const float*)d_in[7];
  const float* tnb = (const float*)d_in[8];

  char* ws = (char*)d_ws;
  uint16_t* Aq = (uint16_t*)(ws + OFF_AQ);
  uint16_t* W1q = (uint16_t*)(ws + OFF_W1Q);
  int8_t* W2q = (int8_t*)(ws + OFF_W2Q);
  short* C1 = (short*)(ws + OFF_C1);
  int8_t* t8 = (int8_t*)(ws + OFF_T8);
  int* colsum = (int*)(ws + OFF_STATS);
  ull* colsq = (ull*)(ws + OFF_STATS + 4096);
  int* sum2 = (int*)(ws + OFF_STATS + 12288);
  ull* sq2 = (ull*)(ws + OFF_STATS + 12352);
  int* gsum = (int*)(ws + OFF_STATS + 12480);
  int* gsq = (int*)(ws + OFF_STATS + 12484);
  double* dmean = (double*)(ws + OFF_BN1);
  double* dinv = (double*)(ws + OFF_BN1 + 8192);
  int* C2 = (int*)(ws + OFF_C2);
  int8_t* t2 = (int8_t*)(ws + OFF_T2);

  hipMemsetAsync(ws + OFF_STATS, 0, SZ_STATS, stream);

  int totalq = BB * KP + N1 * KP + N2 * N1;
  k0_quant<<<(totalq + 255) / 256, 256, 0, stream>>>(x, W1, W2, Aq, W1q, W2q);
  k1_gemm1<<<dim3(8, 128), 256, 0, stream>>>(Aq, W1q, C1);
  k2_stats1<<<dim3(4, 64), 256, 0, stream>>>(C1, colsum, colsq);
  k3_bn1<<<1, 1024, 0, stream>>>(colsum, colsq, dmean, dinv);
  k4_bnq<<<BB * N1 / 4 / 256, 256, 0, stream>>>(C1, dmean, dinv, g1, b1, t8);
  k5_gemm2<<<1024, 256, 0, stream>>>(t8, W2q, C2, sum2, sq2);
  k7_bn2q<<<NTOT / 256, 256, 0, stream>>>(C2, sum2, sq2, g2, b2, t2, gsum, gsq);
  k9_out<<<NTOT / 256, 256, 0, stream>>>(t2, gsum, gsq, tnw, tnb, (float*)d_out);
}

// Round 2
// 209.909 us; speedup vs baseline: 1.1739x; 1.1739x over previous
//
#include <hip/hip_runtime.h>
#include <stdint.h>

typedef int i32x4 __attribute__((ext_vector_type(4)));
typedef short s16x8 __attribute__((ext_vector_type(8)));
typedef unsigned long long ull;

#define BB 16384
#define KD 784
#define KP 832  // padded to multiple of 64
#define N1 1024
#define N2 10
#define NTOT (BB * N2)  // 163840

// ---- workspace layout (bytes) ----
#define OFF_AQ 0ULL
#define SZ_AQ (13631488ULL)  // 16384*832 i8
#define OFF_W1Q (OFF_AQ + SZ_AQ)
#define SZ_W1Q (851968ULL)  // 1024*832 i8
#define OFF_W2Q (OFF_W1Q + SZ_W1Q)
#define SZ_W2Q (16384ULL)  // 10*1024 i8 (padded)
#define OFF_C1 (OFF_W2Q + SZ_W2Q)
#define SZ_C1 (33554432ULL)  // 16384*1024 i16
#define OFF_T8 (OFF_C1 + SZ_C1)
#define SZ_T8 (16777216ULL)  // 16384*1024 i8
#define OFF_STATS (OFF_T8 + SZ_T8)
#define SZ_STATS (16384ULL)
// stats sublayout: colsum int[1024] @0; colsq ull[1024] @4096; sum2 int[16] @12288;
//                  sq2 ull[16] @12352; gsum int @12480; gsq int @12484
#define OFF_BN1 (OFF_STATS + SZ_STATS)
#define SZ_BN1 (16384ULL)  // Ac double[1024] @0 + Bc double[1024] @8192
#define OFF_C2 (OFF_BN1 + SZ_BN1)
#define SZ_C2 (655360ULL)  // 16384*10 int
#define OFF_T2 (OFF_C2 + SZ_C2)
#define SZ_T2 (163840ULL)  // i8

__device__ __forceinline__ void async16(const void* g, void* l) {
  __builtin_amdgcn_global_load_lds((__attribute__((address_space(1))) void*)(void*)(g),
                                   (__attribute__((address_space(3))) void*)(l), 16, 0, 0);
}

__device__ __forceinline__ int8_t ternq(float v) {
  float q = rintf(v);
  return q > 0.5f ? 1 : (q < -0.5f ? -1 : 0);
}

__device__ __forceinline__ int dot4(int a, int b, int c) {
#if __has_builtin(__builtin_amdgcn_sdot4)
  return __builtin_amdgcn_sdot4(a, b, c, false);
#else
  const int8_t* pa = (const int8_t*)&a;
  const int8_t* pb = (const int8_t*)&b;
  return c + (int)pa[0] * pb[0] + (int)pa[1] * pb[1] + (int)pa[2] * pb[2] + (int)pa[3] * pb[3];
#endif
}

// K0: quantize x -> Aq (i8, K padded to 832), W1 -> W1q (i8 padded), W2 -> W2q (i8)
// 16 elements per thread, float4 loads, int4 stores.
__global__ void k0_quant(const float* __restrict__ x, const float* __restrict__ W1,
                         const float* __restrict__ W2, int8_t* __restrict__ Aq,
                         int8_t* __restrict__ W1q, int8_t* __restrict__ W2q) {
  const int TA = BB * KP / 16;  // 851968
  const int TW = N1 * KP / 16;  // 53248
  const int T2 = N2 * N1 / 16;  // 640
  int tid = blockIdx.x * 256 + threadIdx.x;
  union {
    int4 v;
    int8_t b[16];
  } o;
  o.v = make_int4(0, 0, 0, 0);
  if (tid < TA) {
    int base = tid * 16;
    int r = base / KP, k = base - r * KP;
    if (k < KD) {
      const float4* xp = (const float4*)&x[r * KD + k];
#pragma unroll
      for (int g = 0; g < 4; ++g) {
        float4 f = xp[g];
        o.b[g * 4 + 0] = ternq(2.0f * f.x - 1.0f);
        o.b[g * 4 + 1] = ternq(2.0f * f.y - 1.0f);
        o.b[g * 4 + 2] = ternq(2.0f * f.z - 1.0f);
        o.b[g * 4 + 3] = ternq(2.0f * f.w - 1.0f);
      }
    }
    *(int4*)&Aq[base] = o.v;
  } else if (tid < TA + TW) {
    int base = (tid - TA) * 16;
    int r = base / KP, k = base - r * KP;
    if (k < KD) {
      const float4* wp = (const float4*)&W1[r * KD + k];
#pragma unroll
      for (int g = 0; g < 4; ++g) {
        float4 f = wp[g];
        o.b[g * 4 + 0] = ternq(f.x);
        o.b[g * 4 + 1] = ternq(f.y);
        o.b[g * 4 + 2] = ternq(f.z);
        o.b[g * 4 + 3] = ternq(f.w);
      }
    }
    *(int4*)&W1q[base] = o.v;
  } else if (tid < TA + TW + T2) {
    int base = (tid - TA - TW) * 16;
    const float4* wp = (const float4*)&W2[base];
#pragma unroll
    for (int g = 0; g < 4; ++g) {
      float4 f = wp[g];
      o.b[g * 4 + 0] = ternq(f.x);
      o.b[g * 4 + 1] = ternq(f.y);
      o.b[g * 4 + 2] = ternq(f.z);
      o.b[g * 4 + 3] = ternq(f.w);
    }
    *(int4*)&W2q[base] = o.v;
  }
}

// K1: C1 = Aq @ W1q^T  (128x128 tile, i8 MFMA 16x16x64, exact int) + fused col stats.
// LDS granule XOR swizzle (g ^= (row>>1)&3) applied on the GLOBAL source address so the
// global_load_lds lane-contiguity constraint is preserved; reads undo it identically.
__global__ __launch_bounds__(256, 2) void k1_gemm1(const int8_t* __restrict__ Aq,
                                                   const int8_t* __restrict__ W1q,
                                                   short* __restrict__ C1,
                                                   int* __restrict__ colsum,
                                                   ull* __restrict__ colsq) {
  __shared__ int8_t As[128 * 64];
  __shared__ int8_t Bs[128 * 64];
  __shared__ int cS[128];
  __shared__ int cQ[128];
  const int t = threadIdx.x;
  const int lane = t & 63, wave = t >> 6;
  const int wr = wave >> 1, wc = wave & 1;
  const int rowBase = blockIdx.y * 128, colBase = blockIdx.x * 128;
  if (t < 128) {
    cS[t] = 0;
    cQ[t] = 0;
  }

  i32x4 acc[4][4] = {};

  const int r0 = t >> 2;
  const int gsrc = ((t & 3) ^ ((t >> 3) & 3)) * 16;  // swizzled global granule
  const int m = lane & 15;
  const int goff = ((lane >> 4) ^ ((m >> 1) & 3)) * 16;  // swizzled LDS read granule

  for (int kt = 0; kt < KP / 64; ++kt) {
    __syncthreads();
    const int kb = kt * 64;
    async16(&Aq[(size_t)(rowBase + r0) * KP + kb + gsrc], &As[t * 16]);
    async16(&Aq[(size_t)(rowBase + r0 + 64) * KP + kb + gsrc], &As[4096 + t * 16]);
    async16(&W1q[(size_t)(colBase + r0) * KP + kb + gsrc], &Bs[t * 16]);
    async16(&W1q[(size_t)(colBase + r0 + 64) * KP + kb + gsrc], &Bs[4096 + t * 16]);
    __syncthreads();
    i32x4 av[4], bv[4];
#pragma unroll
    for (int i = 0; i < 4; ++i) av[i] = *(const i32x4*)&As[(64 * wr + 16 * i + m) * 64 + goff];
#pragma unroll
    for (int j = 0; j < 4; ++j) bv[j] = *(const i32x4*)&Bs[(64 * wc + 16 * j + m) * 64 + goff];
#pragma unroll
    for (int i = 0; i < 4; ++i)
#pragma unroll
      for (int j = 0; j < 4; ++j)
        acc[i][j] = __builtin_amdgcn_mfma_i32_16x16x64_i8(av[i], bv[j], acc[i][j], 0, 0, 0);
  }

  // epilogue: store C1 (i16) + per-column partial sum/sumsq into LDS
  const int q = lane >> 4, cl = lane & 15;
#pragma unroll
  for (int j = 0; j < 4; ++j) {
    const int colLoc = 64 * wc + 16 * j + cl;
    const int col = colBase + colLoc;
    int s = 0, sq = 0;
#pragma unroll
    for (int i = 0; i < 4; ++i) {
#pragma unroll
      for (int rg = 0; rg < 4; ++rg) {
        int v = acc[i][j][rg];
        int row = rowBase + 64 * wr + 16 * i + q * 4 + rg;
        C1[(size_t)row * N1 + col] = (short)v;
        s += v;
        sq += v * v;  // <= 128 * 784^2 = 7.9e7, fits int32 per block
      }
    }
    atomicAdd(&cS[colLoc], s);
    atomicAdd(&cQ[colLoc], sq);
  }
  __syncthreads();
  if (t < 128) {
    atomicAdd(&colsum[colBase + t], cS[t]);
    atomicAdd(&colsq[colBase + t], (ull)(unsigned)cQ[t]);
  }
}

// K3: fused BN1 affine constants in double: z = v*Ac + Bc
__global__ void k3_bn1(const int* __restrict__ colsum, const ull* __restrict__ colsq,
                       const float* __restrict__ g1, const float* __restrict__ b1,
                       double* __restrict__ Ac, double* __restrict__ Bc) {
  int c = blockIdx.x * 256 + threadIdx.x;  // grid 4x256
  double mean = (double)colsum[c] / 16384.0;
  double var = (double)colsq[c] / 16384.0 - mean * mean;
  double dinv = 1.0 / sqrt(var + 1e-5);
  double a = dinv * (double)g1[c];
  Ac[c] = a;
  Bc[c] = (double)b1[c] - mean * a;
}

// K4: t8 = ternary(v*Ac + Bc), 8 elems/thread (16B load, 8B store)
__global__ void k4_bnq(const short* __restrict__ C1, const double* __restrict__ Ac,
                       const double* __restrict__ Bc, int8_t* __restrict__ t8) {
  int id = blockIdx.x * 256 + threadIdx.x;  // 2,097,152 threads
  int base = id * 8;
  int c0 = base & (N1 - 1);
  s16x8 v = *(const s16x8*)&C1[base];
  union {
    ull u;
    int8_t b[8];
  } o;
#pragma unroll
  for (int u = 0; u < 8; ++u) {
    int c = c0 + u;
    double z = (double)v[u] * Ac[c] + Bc[c];
    double qq = rint(z);
    qq = qq < -1.0 ? -1.0 : (qq > 1.0 ? 1.0 : qq);
    o.b[u] = (int8_t)qq;
  }
  *(ull*)&t8[base] = o.u;
}

// K5: C2 = t8 @ W2q^T (wave-per-row, register W2, sdot4) + exact col stats
__global__ __launch_bounds__(256) void k5_gemm2(const int8_t* __restrict__ t8,
                                                const int8_t* __restrict__ W2q,
                                                int* __restrict__ C2, int* __restrict__ sum2,
                                                ull* __restrict__ sq2) {
  __shared__ int ls[N2];
  __shared__ ull lq[N2];
  int t = threadIdx.x;
  if (t < N2) {
    ls[t] = 0;
    lq[t] = 0;
  }
  __syncthreads();
  int lane = t & 63, wave = t >> 6;
  int4 w2r[N2];
#pragma unroll
  for (int c = 0; c < N2; ++c) w2r[c] = *(const int4*)&W2q[c * N1 + lane * 16];
  int gw = blockIdx.x * 4 + wave;
  for (int r = gw; r < BB; r += gridDim.x * 4) {
    int4 a = *(const int4*)&t8[(size_t)r * N1 + lane * 16];
    int s[N2];
#pragma unroll
    for (int c = 0; c < N2; ++c)
      s[c] = dot4(a.x, w2r[c].x, dot4(a.y, w2r[c].y, dot4(a.z, w2r[c].z, dot4(a.w, w2r[c].w, 0))));
#pragma unroll
    for (int c = 0; c < N2; ++c) {
#pragma unroll
      for (int off = 32; off > 0; off >>= 1) s[c] += __shfl_xor(s[c], off, 64);
    }
    if (lane == 0) {
#pragma unroll
      for (int c = 0; c < N2; ++c) {
        C2[r * N2 + c] = s[c];
        atomicAdd(&ls[c], s[c]);
        atomicAdd(&lq[c], (ull)((long long)s[c] * s[c]));
      }
    }
  }
  __syncthreads();
  if (t < N2) {
    atomicAdd(&sum2[t], ls[t]);
    atomicAdd(&sq2[t], lq[t]);
  }
}

// K7: t2 = ternary(batchnorm2(C2)) + global sum/sumsq of t2 (exact int)
__global__ void k7_bn2q(const int* __restrict__ C2, const int* __restrict__ sum2,
                        const ull* __restrict__ sq2, const float* __restrict__ g2,
                        const float* __restrict__ b2, int8_t* __restrict__ t2,
                        int* __restrict__ gsum, int* __restrict__ gsq) {
  int id = blockIdx.x * 256 + threadIdx.x;  // 163840 total
  int c = id % N2;
  int v = C2[id];
  double mean = (double)sum2[c] / 16384.0;
  double var = (double)sq2[c] / 16384.0 - mean * mean;
  double z = ((double)v - mean) / sqrt(var + 1e-5) * (double)g2[c] + (double)b2[c];
  double qq = rint(z);
  qq = qq < -1.0 ? -1.0 : (qq > 1.0 ? 1.0 : qq);
  int ti = (int)qq;
  t2[id] = (int8_t)ti;
  int s = ti, sq = ti * ti;
#pragma unroll
  for (int off = 32; off > 0; off >>= 1) {
    s += __shfl_xor(s, off, 64);
    sq += __shfl_xor(sq, off, 64);
  }
  __shared__ int bs, bq;
  if (threadIdx.x == 0) {
    bs = 0;
    bq = 0;
  }
  __syncthreads();
  if ((threadIdx.x & 63) == 0) {
    atomicAdd(&bs, s);
    atomicAdd(&bq, sq);
  }
  __syncthreads();
  if (threadIdx.x == 0) {
    atomicAdd(gsum, bs);
    atomicAdd(gsq, bq);
  }
}

// K9: out = tensornorm(t2)  (unbiased var, eps=1e-4)
__global__ void k9_out(const int8_t* __restrict__ t2, const int* __restrict__ gsum,
                       const int* __restrict__ gsq, const float* __restrict__ tn_w,
                       const float* __restrict__ tn_b, float* __restrict__ out) {
  int id = blockIdx.x * 256 + threadIdx.x;
  double n = (double)NTOT;
  double sm = (double)*gsum;
  double mean = sm / n;
  double var = ((double)*gsq - sm * sm / n) / (n - 1.0);
  double alpha = (double)tn_w[0] / sqrt(var + 1e-4);
  out[id] = (float)(((double)t2[id] - mean) * alpha + (double)tn_b[0]);
}

extern "C" void kernel_launch(void* const* d_in, const int* in_sizes, int n_in, void* d_out,
                              int out_size, void* d_ws, size_t ws_size, hipStream_t stream) {
  const float* x = (const float*)d_in[0];
  const float* W1 = (const float*)d_in[1];
  const float* g1 = (const float*)d_in[2];
  const float* b1 = (const float*)d_in[3];
  const float* W2 = (const float*)d_in[4];
  const float* g2 = (const float*)d_in[5];
  const float* b2 = (const float*)d_in[6];
  const float* tnw = (const float*)d_in[7];
  const float* tnb = (const float*)d_in[8];

  char* ws = (char*)d_ws;
  int8_t* Aq = (int8_t*)(ws + OFF_AQ);
  int8_t* W1q = (int8_t*)(ws + OFF_W1Q);
  int8_t* W2q = (int8_t*)(ws + OFF_W2Q);
  short* C1 = (short*)(ws + OFF_C1);
  int8_t* t8 = (int8_t*)(ws + OFF_T8);
  int* colsum = (int*)(ws + OFF_STATS);
  ull* colsq = (ull*)(ws + OFF_STATS + 4096);
  int* sum2 = (int*)(ws + OFF_STATS + 12288);
  ull* sq2 = (ull*)(ws + OFF_STATS + 12352);
  int* gsum = (int*)(ws + OFF_STATS + 12480);
  int* gsq = (int*)(ws + OFF_STATS + 12484);
  double* Ac = (double*)(ws + OFF_BN1);
  double* Bc = (double*)(ws + OFF_BN1 + 8192);
  int* C2 = (int*)(ws + OFF_C2);
  int8_t* t2 = (int8_t*)(ws + OFF_T2);

  hipMemsetAsync(ws + OFF_STATS, 0, SZ_STATS, stream);

  const int totalT = BB * KP / 16 + N1 * KP / 16 + N2 * N1 / 16;  // 905856
  k0_quant<<<(totalT + 255) / 256, 256, 0, stream>>>(x, W1, W2, Aq, W1q, W2q);
  k1_gemm1<<<dim3(8, 128), 256, 0, stream>>>(Aq, W1q, C1, colsum, colsq);
  k3_bn1<<<4, 256, 0, stream>>>(colsum, colsq, g1, b1, Ac, Bc);
  k4_bnq<<<BB * N1 / 8 / 256, 256, 0, stream>>>(C1, Ac, Bc, t8);
  k5_gemm2<<<2048, 256, 0, stream>>>(t8, W2q, C2, sum2, sq2);
  k7_bn2q<<<NTOT / 256, 256, 0, stream>>>(C2, sum2, sq2, g2, b2, t2, gsum, gsq);
  k9_out<<<NTOT / 256, 256, 0, stream>>>(t2, gsum, gsq, tnw, tnb, (float*)d_out);
}

// Round 3
// 168.268 us; speedup vs baseline: 1.4645x; 1.2475x over previous
//
#include <hip/hip_runtime.h>
#include <stdint.h>

typedef int i32x4 __attribute__((ext_vector_type(4)));
typedef short s16x8 __attribute__((ext_vector_type(8)));
typedef unsigned long long ull;

#define BB 16384
#define KD 784
#define KP 832  // padded to multiple of 64
#define N1 1024
#define N2 10
#define NTOT (BB * N2)  // 163840

// ---- workspace layout (bytes) ----
#define OFF_AQ 0ULL
#define SZ_AQ (13631488ULL)  // 16384*832 i8
#define OFF_W1Q (OFF_AQ + SZ_AQ)
#define SZ_W1Q (851968ULL)  // 1024*832 i8
#define OFF_W2Q (OFF_W1Q + SZ_W1Q)
#define SZ_W2Q (16384ULL)  // 16*1024 i8 (rows 10..15 are poison; masked out downstream)
#define OFF_C1 (OFF_W2Q + SZ_W2Q)
#define SZ_C1 (33554432ULL)  // 16384*1024 i16
#define OFF_T8 (OFF_C1 + SZ_C1)
#define SZ_T8 (16777216ULL)  // 16384*1024 i8
#define OFF_STATS (OFF_T8 + SZ_T8)
#define SZ_STATS (16384ULL)
// stats sublayout (bytes): colsum int[1024] @0; colsq ull[1024] @4096;
//   sum2p int, stride 16 ints (64B), 16 entries @12288;
//   sq2p  ull, stride 8 ulls (64B), 16 entries @13312;
//   gsum int @14336; gsq int @14400  (separate cache lines)
#define OFF_BN1 (OFF_STATS + SZ_STATS)
#define SZ_BN1 (16384ULL)  // Ac double[1024] @0 + Bc double[1024] @8192
#define OFF_C2 (OFF_BN1 + SZ_BN1)
#define SZ_C2 (1048576ULL)  // 16384*16 int (padded cols)
#define OFF_T2 (OFF_C2 + SZ_C2)
#define SZ_T2 (163840ULL)  // i8

__device__ __forceinline__ void async16(const void* g, void* l) {
  __builtin_amdgcn_global_load_lds((__attribute__((address_space(1))) void*)(void*)(g),
                                   (__attribute__((address_space(3))) void*)(l), 16, 0, 0);
}

__device__ __forceinline__ int8_t ternq(float v) {
  float q = rintf(v);
  return q > 0.5f ? 1 : (q < -0.5f ? -1 : 0);
}

// K0: quantize x -> Aq (i8, K padded to 832), W1 -> W1q (i8 padded), W2 -> W2q (i8)
__global__ void k0_quant(const float* __restrict__ x, const float* __restrict__ W1,
                         const float* __restrict__ W2, int8_t* __restrict__ Aq,
                         int8_t* __restrict__ W1q, int8_t* __restrict__ W2q) {
  const int TA = BB * KP / 16;  // 851968
  const int TW = N1 * KP / 16;  // 53248
  const int T2 = N2 * N1 / 16;  // 640
  int tid = blockIdx.x * 256 + threadIdx.x;
  union {
    int4 v;
    int8_t b[16];
  } o;
  o.v = make_int4(0, 0, 0, 0);
  if (tid < TA) {
    int base = tid * 16;
    int r = base / KP, k = base - r * KP;
    if (k < KD) {
      const float4* xp = (const float4*)&x[r * KD + k];
#pragma unroll
      for (int g = 0; g < 4; ++g) {
        float4 f = xp[g];
        o.b[g * 4 + 0] = ternq(2.0f * f.x - 1.0f);
        o.b[g * 4 + 1] = ternq(2.0f * f.y - 1.0f);
        o.b[g * 4 + 2] = ternq(2.0f * f.z - 1.0f);
        o.b[g * 4 + 3] = ternq(2.0f * f.w - 1.0f);
      }
    }
    *(int4*)&Aq[base] = o.v;
  } else if (tid < TA + TW) {
    int base = (tid - TA) * 16;
    int r = base / KP, k = base - r * KP;
    if (k < KD) {
      const float4* wp = (const float4*)&W1[r * KD + k];
#pragma unroll
      for (int g = 0; g < 4; ++g) {
        float4 f = wp[g];
        o.b[g * 4 + 0] = ternq(f.x);
        o.b[g * 4 + 1] = ternq(f.y);
        o.b[g * 4 + 2] = ternq(f.z);
        o.b[g * 4 + 3] = ternq(f.w);
      }
    }
    *(int4*)&W1q[base] = o.v;
  } else if (tid < TA + TW + T2) {
    int base = (tid - TA - TW) * 16;
    const float4* wp = (const float4*)&W2[base];
#pragma unroll
    for (int g = 0; g < 4; ++g) {
      float4 f = wp[g];
      o.b[g * 4 + 0] = ternq(f.x);
      o.b[g * 4 + 1] = ternq(f.y);
      o.b[g * 4 + 2] = ternq(f.z);
      o.b[g * 4 + 3] = ternq(f.w);
    }
    *(int4*)&W2q[base] = o.v;
  }
}

// K1: C1 = Aq @ W1q^T  (128x128 tile, i8 MFMA 16x16x64, exact int) + fused col stats.
__global__ __launch_bounds__(256, 2) void k1_gemm1(const int8_t* __restrict__ Aq,
                                                   const int8_t* __restrict__ W1q,
                                                   short* __restrict__ C1,
                                                   int* __restrict__ colsum,
                                                   ull* __restrict__ colsq) {
  __shared__ int8_t As[128 * 64];
  __shared__ int8_t Bs[128 * 64];
  __shared__ int cS[128];
  __shared__ int cQ[128];
  const int t = threadIdx.x;
  const int lane = t & 63, wave = t >> 6;
  const int wr = wave >> 1, wc = wave & 1;
  const int rowBase = blockIdx.y * 128, colBase = blockIdx.x * 128;
  if (t < 128) {
    cS[t] = 0;
    cQ[t] = 0;
  }

  i32x4 acc[4][4] = {};

  const int r0 = t >> 2;
  const int gsrc = ((t & 3) ^ ((t >> 3) & 3)) * 16;  // swizzled global granule
  const int m = lane & 15;
  const int goff = ((lane >> 4) ^ ((m >> 1) & 3)) * 16;  // swizzled LDS read granule

  for (int kt = 0; kt < KP / 64; ++kt) {
    __syncthreads();
    const int kb = kt * 64;
    async16(&Aq[(size_t)(rowBase + r0) * KP + kb + gsrc], &As[t * 16]);
    async16(&Aq[(size_t)(rowBase + r0 + 64) * KP + kb + gsrc], &As[4096 + t * 16]);
    async16(&W1q[(size_t)(colBase + r0) * KP + kb + gsrc], &Bs[t * 16]);
    async16(&W1q[(size_t)(colBase + r0 + 64) * KP + kb + gsrc], &Bs[4096 + t * 16]);
    __syncthreads();
    i32x4 av[4], bv[4];
#pragma unroll
    for (int i = 0; i < 4; ++i) av[i] = *(const i32x4*)&As[(64 * wr + 16 * i + m) * 64 + goff];
#pragma unroll
    for (int j = 0; j < 4; ++j) bv[j] = *(const i32x4*)&Bs[(64 * wc + 16 * j + m) * 64 + goff];
#pragma unroll
    for (int i = 0; i < 4; ++i)
#pragma unroll
      for (int j = 0; j < 4; ++j)
        acc[i][j] = __builtin_amdgcn_mfma_i32_16x16x64_i8(av[i], bv[j], acc[i][j], 0, 0, 0);
  }

  // epilogue: store C1 (i16) + per-column partial sum/sumsq into LDS
  const int q = lane >> 4, cl = lane & 15;
#pragma unroll
  for (int j = 0; j < 4; ++j) {
    const int colLoc = 64 * wc + 16 * j + cl;
    const int col = colBase + colLoc;
    int s = 0, sq = 0;
#pragma unroll
    for (int i = 0; i < 4; ++i) {
#pragma unroll
      for (int rg = 0; rg < 4; ++rg) {
        int v = acc[i][j][rg];
        int row = rowBase + 64 * wr + 16 * i + q * 4 + rg;
        C1[(size_t)row * N1 + col] = (short)v;
        s += v;
        sq += v * v;  // <= 128 * 784^2 = 7.9e7, fits int32 per block
      }
    }
    atomicAdd(&cS[colLoc], s);
    atomicAdd(&cQ[colLoc], sq);
  }
  __syncthreads();
  if (t < 128) {
    atomicAdd(&colsum[colBase + t], cS[t]);
    atomicAdd(&colsq[colBase + t], (ull)(unsigned)cQ[t]);
  }
}

// K3: fused BN1 affine constants in double: z = v*Ac + Bc
__global__ void k3_bn1(const int* __restrict__ colsum, const ull* __restrict__ colsq,
                       const float* __restrict__ g1, const float* __restrict__ b1,
                       double* __restrict__ Ac, double* __restrict__ Bc) {
  int c = blockIdx.x * 256 + threadIdx.x;  // grid 4x256
  double mean = (double)colsum[c] / 16384.0;
  double var = (double)colsq[c] / 16384.0 - mean * mean;
  double dinv = 1.0 / sqrt(var + 1e-5);
  double a = dinv * (double)g1[c];
  Ac[c] = a;
  Bc[c] = (double)b1[c] - mean * a;
}

// K4: t8 = ternary(v*Ac + Bc), 8 elems/thread (16B load, 8B store)
__global__ void k4_bnq(const short* __restrict__ C1, const double* __restrict__ Ac,
                       const double* __restrict__ Bc, int8_t* __restrict__ t8) {
  int id = blockIdx.x * 256 + threadIdx.x;  // 2,097,152 threads
  int base = id * 8;
  int c0 = base & (N1 - 1);
  s16x8 v = *(const s16x8*)&C1[base];
  union {
    ull u;
    int8_t b[8];
  } o;
#pragma unroll
  for (int u = 0; u < 8; ++u) {
    int c = c0 + u;
    double z = (double)v[u] * Ac[c] + Bc[c];
    double qq = rint(z);
    qq = qq < -1.0 ? -1.0 : (qq > 1.0 ? 1.0 : qq);
    o.b[u] = (int8_t)qq;
  }
  *(ull*)&t8[base] = o.u;
}

// K5: C2 = t8 @ W2q^T via i8 MFMA (one wave = one 16x16 tile, K=1024) + col stats.
// W2 fragments straight from global (L1/L2 broadcast). No shuffles.
__global__ __launch_bounds__(256) void k5_gemm2(const int8_t* __restrict__ t8,
                                                const int8_t* __restrict__ W2q,
                                                int* __restrict__ C2,
                                                int* __restrict__ sum2p,
                                                ull* __restrict__ sq2p) {
  __shared__ int cS[16];
  __shared__ int cQ[16];
  const int t = threadIdx.x;
  if (t < 16) {
    cS[t] = 0;
    cQ[t] = 0;
  }
  const int lane = t & 63, wave = t >> 6;
  const int n = lane & 15, kc = lane >> 4;

  i32x4 bfr[16];
#pragma unroll
  for (int kt = 0; kt < 16; ++kt)
    bfr[kt] = *(const i32x4*)&W2q[n * N1 + kt * 64 + kc * 16];

  const int tile = blockIdx.x * 4 + wave;  // 0..1023
  const int rowBase = tile * 16;
  i32x4 acc = {0, 0, 0, 0};
#pragma unroll
  for (int kt = 0; kt < 16; ++kt) {
    i32x4 a = *(const i32x4*)&t8[(size_t)(rowBase + n) * N1 + kt * 64 + kc * 16];
    acc = __builtin_amdgcn_mfma_i32_16x16x64_i8(a, bfr[kt], acc, 0, 0, 0);
  }
  // C/D layout: col = lane&15, row = (lane>>4)*4 + reg
  const int col = n;
  int s = 0, sq = 0;
#pragma unroll
  for (int rg = 0; rg < 4; ++rg) {
    int row = rowBase + kc * 4 + rg;
    C2[row * 16 + col] = acc[rg];
  }
  if (col < N2) {
#pragma unroll
    for (int rg = 0; rg < 4; ++rg) {
      int v = acc[rg];
      s += v;
      sq += v * v;  // |v|<=1024 -> sq per lane <= 4*1.05e6, block <= 6.8e7, int ok
    }
    atomicAdd(&cS[col], s);
    atomicAdd(&cQ[col], sq);
  }
  __syncthreads();
  if (t < N2) {
    atomicAdd(&sum2p[t * 16], cS[t]);
    atomicAdd(&sq2p[t * 8], (ull)(unsigned)cQ[t]);
  }
}

// K7: t2 = ternary(batchnorm2(C2)) + global sum/sumsq of t2 (exact int).
// Grid-stride with few blocks to keep gsum/gsq atomic serialization short.
__global__ __launch_bounds__(256) void k7_bn2q(const int* __restrict__ C2,
                                               const int* __restrict__ sum2p,
                                               const ull* __restrict__ sq2p,
                                               const float* __restrict__ g2,
                                               const float* __restrict__ b2,
                                               int8_t* __restrict__ t2, int* __restrict__ gsum,
                                               int* __restrict__ gsq) {
  int s = 0, sq = 0;
  for (int id = blockIdx.x * 256 + threadIdx.x; id < NTOT; id += gridDim.x * 256) {
    int r = id / N2, c = id - r * N2;
    int v = C2[r * 16 + c];
    double mean = (double)sum2p[c * 16] / 16384.0;
    double var = (double)sq2p[c * 8] / 16384.0 - mean * mean;
    double z = ((double)v - mean) / sqrt(var + 1e-5) * (double)g2[c] + (double)b2[c];
    double qq = rint(z);
    qq = qq < -1.0 ? -1.0 : (qq > 1.0 ? 1.0 : qq);
    int ti = (int)qq;
    t2[id] = (int8_t)ti;
    s += ti;
    sq += ti * ti;
  }
#pragma unroll
  for (int off = 32; off > 0; off >>= 1) {
    s += __shfl_xor(s, off, 64);
    sq += __shfl_xor(sq, off, 64);
  }
  __shared__ int bs, bq;
  if (threadIdx.x == 0) {
    bs = 0;
    bq = 0;
  }
  __syncthreads();
  if ((threadIdx.x & 63) == 0) {
    atomicAdd(&bs, s);
    atomicAdd(&bq, sq);
  }
  __syncthreads();
  if (threadIdx.x == 0) {
    atomicAdd(gsum, bs);
    atomicAdd(gsq, bq);
  }
}

// K9: out = tensornorm(t2)  (unbiased var, eps=1e-4)
__global__ void k9_out(const int8_t* __restrict__ t2, const int* __restrict__ gsum,
                       const int* __restrict__ gsq, const float* __restrict__ tn_w,
                       const float* __restrict__ tn_b, float* __restrict__ out) {
  int id = blockIdx.x * 256 + threadIdx.x;
  double n = (double)NTOT;
  double sm = (double)*gsum;
  double mean = sm / n;
  double var = ((double)*gsq - sm * sm / n) / (n - 1.0);
  double alpha = (double)tn_w[0] / sqrt(var + 1e-4);
  out[id] = (float)(((double)t2[id] - mean) * alpha + (double)tn_b[0]);
}

extern "C" void kernel_launch(void* const* d_in, const int* in_sizes, int n_in, void* d_out,
                              int out_size, void* d_ws, size_t ws_size, hipStream_t stream) {
  const float* x = (const float*)d_in[0];
  const float* W1 = (const float*)d_in[1];
  const float* g1 = (const float*)d_in[2];
  const float* b1 = (const float*)d_in[3];
  const float* W2 = (const float*)d_in[4];
  const float* g2 = (const float*)d_in[5];
  const float* b2 = (const float*)d_in[6];
  const float* tnw = (const float*)d_in[7];
  const float* tnb = (const float*)d_in[8];

  char* ws = (char*)d_ws;
  int8_t* Aq = (int8_t*)(ws + OFF_AQ);
  int8_t* W1q = (int8_t*)(ws + OFF_W1Q);
  int8_t* W2q = (int8_t*)(ws + OFF_W2Q);
  short* C1 = (short*)(ws + OFF_C1);
  int8_t* t8 = (int8_t*)(ws + OFF_T8);
  int* colsum = (int*)(ws + OFF_STATS);
  ull* colsq = (ull*)(ws + OFF_STATS + 4096);
  int* sum2p = (int*)(ws + OFF_STATS + 12288);
  ull* sq2p = (ull*)(ws + OFF_STATS + 13312);
  int* gsum = (int*)(ws + OFF_STATS + 14336);
  int* gsq = (int*)(ws + OFF_STATS + 14400);
  double* Ac = (double*)(ws + OFF_BN1);
  double* Bc = (double*)(ws + OFF_BN1 + 8192);
  int* C2 = (int*)(ws + OFF_C2);
  int8_t* t2 = (int8_t*)(ws + OFF_T2);

  hipMemsetAsync(ws + OFF_STATS, 0, SZ_STATS, stream);

  const int totalT = BB * KP / 16 + N1 * KP / 16 + N2 * N1 / 16;  // 905856
  k0_quant<<<(totalT + 255) / 256, 256, 0, stream>>>(x, W1, W2, Aq, W1q, W2q);
  k1_gemm1<<<dim3(8, 128), 256, 0, stream>>>(Aq, W1q, C1, colsum, colsq);
  k3_bn1<<<4, 256, 0, stream>>>(colsum, colsq, g1, b1, Ac, Bc);
  k4_bnq<<<BB * N1 / 8 / 256, 256, 0, stream>>>(C1, Ac, Bc, t8);
  k5_gemm2<<<256, 256, 0, stream>>>(t8, W2q, C2, sum2p, sq2p);
  k7_bn2q<<<160, 256, 0, stream>>>(C2, sum2p, sq2p, g2, b2, t2, gsum, gsq);
  k9_out<<<NTOT / 256, 256, 0, stream>>>(t2, gsum, gsq, tnw, tnb, (float*)d_out);
}

// Round 4
// 157.834 us; speedup vs baseline: 1.5613x; 1.0661x over previous
//
#include <hip/hip_runtime.h>
#include <stdint.h>

typedef int i32x4 __attribute__((ext_vector_type(4)));
typedef short s16x8 __attribute__((ext_vector_type(8)));
typedef unsigned long long ull;

#define BB 16384
#define KD 784
#define KP 832  // padded to multiple of 64
#define N1 1024
#define N2 10
#define NTOT (BB * N2)  // 163840

// ---- workspace layout (bytes) ----
#define OFF_AQ 0ULL
#define SZ_AQ (13631488ULL)  // 16384*832 i8
#define OFF_W1Q (OFF_AQ + SZ_AQ)
#define SZ_W1Q (851968ULL)  // 1024*832 i8
#define OFF_W2Q (OFF_W1Q + SZ_W1Q)
#define SZ_W2Q (16384ULL)  // 16*1024 i8 (rows 10..15 are poison; masked out downstream)
#define OFF_C1 (OFF_W2Q + SZ_W2Q)
#define SZ_C1 (33554432ULL)  // 16384*1024 i16
#define OFF_STATS (OFF_C1 + SZ_C1)
#define SZ_STATS (16384ULL)
// stats sublayout (bytes): colsum int[1024] @0; colsq ull[1024] @4096;
//   sum2p int, stride 16 ints (64B), 16 entries @12288;
//   sq2p  ull, stride 8 ulls (64B), 16 entries @13312;
//   gsum int @14336; gsq int @14400  (separate cache lines)
#define OFF_BN1 (OFF_STATS + SZ_STATS)
#define SZ_BN1 (16384ULL)  // Ac double[1024] @0 + Bc double[1024] @8192
#define OFF_C2 (OFF_BN1 + SZ_BN1)
#define SZ_C2 (1048576ULL)  // 16384*16 int (padded cols)
#define OFF_T2 (OFF_C2 + SZ_C2)
#define SZ_T2 (163840ULL)  // i8

__device__ __forceinline__ void async16(const void* g, void* l) {
  __builtin_amdgcn_global_load_lds((__attribute__((address_space(1))) void*)(void*)(g),
                                   (__attribute__((address_space(3))) void*)(l), 16, 0, 0);
}

__device__ __forceinline__ int8_t ternq(float v) {
  float q = rintf(v);
  return q > 0.5f ? 1 : (q < -0.5f ? -1 : 0);
}

// K0: quantize x -> Aq (i8, K padded to 832), W1 -> W1q, W2 -> W2q; zero stats region.
__global__ void k0_quant(const float* __restrict__ x, const float* __restrict__ W1,
                         const float* __restrict__ W2, int8_t* __restrict__ Aq,
                         int8_t* __restrict__ W1q, int8_t* __restrict__ W2q,
                         int* __restrict__ stats) {
  const int TA = BB * KP / 16;  // 851968
  const int TW = N1 * KP / 16;  // 53248
  const int T2 = N2 * N1 / 16;  // 640
  int tid = blockIdx.x * 256 + threadIdx.x;
  if (tid < 4096) stats[tid] = 0;  // 16KB stats zeroed (runs before k1 in stream order)
  union {
    int4 v;
    int8_t b[16];
  } o;
  o.v = make_int4(0, 0, 0, 0);
  if (tid < TA) {
    int base = tid * 16;
    int r = base / KP, k = base - r * KP;
    if (k < KD) {
      const float4* xp = (const float4*)&x[r * KD + k];
#pragma unroll
      for (int g = 0; g < 4; ++g) {
        float4 f = xp[g];
        o.b[g * 4 + 0] = ternq(2.0f * f.x - 1.0f);
        o.b[g * 4 + 1] = ternq(2.0f * f.y - 1.0f);
        o.b[g * 4 + 2] = ternq(2.0f * f.z - 1.0f);
        o.b[g * 4 + 3] = ternq(2.0f * f.w - 1.0f);
      }
    }
    *(int4*)&Aq[base] = o.v;
  } else if (tid < TA + TW) {
    int base = (tid - TA) * 16;
    int r = base / KP, k = base - r * KP;
    if (k < KD) {
      const float4* wp = (const float4*)&W1[r * KD + k];
#pragma unroll
      for (int g = 0; g < 4; ++g) {
        float4 f = wp[g];
        o.b[g * 4 + 0] = ternq(f.x);
        o.b[g * 4 + 1] = ternq(f.y);
        o.b[g * 4 + 2] = ternq(f.z);
        o.b[g * 4 + 3] = ternq(f.w);
      }
    }
    *(int4*)&W1q[base] = o.v;
  } else if (tid < TA + TW + T2) {
    int base = (tid - TA - TW) * 16;
    const float4* wp = (const float4*)&W2[base];
#pragma unroll
    for (int g = 0; g < 4; ++g) {
      float4 f = wp[g];
      o.b[g * 4 + 0] = ternq(f.x);
      o.b[g * 4 + 1] = ternq(f.y);
      o.b[g * 4 + 2] = ternq(f.z);
      o.b[g * 4 + 3] = ternq(f.w);
    }
    *(int4*)&W2q[base] = o.v;
  }
}

// K1: C1 = Aq @ W1q^T  (128x128 tile, i8 MFMA 16x16x64, exact int) + fused col stats.
// launch_bounds(256,3): 3 blocks/CU (12 waves) — LDS 17KB/block allows it; VGPR cap ~170.
__global__ __launch_bounds__(256, 3) void k1_gemm1(const int8_t* __restrict__ Aq,
                                                   const int8_t* __restrict__ W1q,
                                                   short* __restrict__ C1,
                                                   int* __restrict__ colsum,
                                                   ull* __restrict__ colsq) {
  __shared__ int8_t As[128 * 64];
  __shared__ int8_t Bs[128 * 64];
  __shared__ int cS[128];
  __shared__ int cQ[128];
  const int t = threadIdx.x;
  const int lane = t & 63, wave = t >> 6;
  const int wr = wave >> 1, wc = wave & 1;
  const int rowBase = blockIdx.y * 128, colBase = blockIdx.x * 128;
  if (t < 128) {
    cS[t] = 0;
    cQ[t] = 0;
  }

  i32x4 acc[4][4] = {};

  const int r0 = t >> 2;
  const int gsrc = ((t & 3) ^ ((t >> 3) & 3)) * 16;  // swizzled global granule
  const int m = lane & 15;
  const int goff = ((lane >> 4) ^ ((m >> 1) & 3)) * 16;  // swizzled LDS read granule

  for (int kt = 0; kt < KP / 64; ++kt) {
    __syncthreads();
    const int kb = kt * 64;
    async16(&Aq[(size_t)(rowBase + r0) * KP + kb + gsrc], &As[t * 16]);
    async16(&Aq[(size_t)(rowBase + r0 + 64) * KP + kb + gsrc], &As[4096 + t * 16]);
    async16(&W1q[(size_t)(colBase + r0) * KP + kb + gsrc], &Bs[t * 16]);
    async16(&W1q[(size_t)(colBase + r0 + 64) * KP + kb + gsrc], &Bs[4096 + t * 16]);
    __syncthreads();
    i32x4 av[4], bv[4];
#pragma unroll
    for (int i = 0; i < 4; ++i) av[i] = *(const i32x4*)&As[(64 * wr + 16 * i + m) * 64 + goff];
#pragma unroll
    for (int j = 0; j < 4; ++j) bv[j] = *(const i32x4*)&Bs[(64 * wc + 16 * j + m) * 64 + goff];
#pragma unroll
    for (int i = 0; i < 4; ++i)
#pragma unroll
      for (int j = 0; j < 4; ++j)
        acc[i][j] = __builtin_amdgcn_mfma_i32_16x16x64_i8(av[i], bv[j], acc[i][j], 0, 0, 0);
  }

  // epilogue: store C1 (i16) + per-column partial sum/sumsq into LDS
  const int q = lane >> 4, cl = lane & 15;
#pragma unroll
  for (int j = 0; j < 4; ++j) {
    const int colLoc = 64 * wc + 16 * j + cl;
    const int col = colBase + colLoc;
    int s = 0, sq = 0;
#pragma unroll
    for (int i = 0; i < 4; ++i) {
#pragma unroll
      for (int rg = 0; rg < 4; ++rg) {
        int v = acc[i][j][rg];
        int row = rowBase + 64 * wr + 16 * i + q * 4 + rg;
        C1[(size_t)row * N1 + col] = (short)v;
        s += v;
        sq += v * v;  // <= 128 * 784^2 = 7.9e7, fits int32 per block
      }
    }
    atomicAdd(&cS[colLoc], s);
    atomicAdd(&cQ[colLoc], sq);
  }
  __syncthreads();
  if (t < 128) {
    atomicAdd(&colsum[colBase + t], cS[t]);
    atomicAdd(&colsq[colBase + t], (ull)(unsigned)cQ[t]);
  }
}

// K3: fused BN1 affine constants in double: z = v*Ac + Bc
__global__ void k3_bn1(const int* __restrict__ colsum, const ull* __restrict__ colsq,
                       const float* __restrict__ g1, const float* __restrict__ b1,
                       double* __restrict__ Ac, double* __restrict__ Bc) {
  int c = blockIdx.x * 256 + threadIdx.x;  // grid 4x256
  double mean = (double)colsum[c] / 16384.0;
  double var = (double)colsq[c] / 16384.0 - mean * mean;
  double dinv = 1.0 / sqrt(var + 1e-5);
  double a = dinv * (double)g1[c];
  Ac[c] = a;
  Bc[c] = (double)b1[c] - mean * a;
}

// K45: fused BN1-ternary + GEMM2 (i8 MFMA, one wave = one 16x16 tile, K=1024) + C2 col stats.
// A-fragment built on the fly from C1 (no t8 materialization). W2 + Ac/Bc staged in LDS.
#define W2S 1040  // LDS row stride for W2 (1040/4=260, 260%32=4 -> 2-way bank alias = free)
__global__ __launch_bounds__(256) void k45_bnq_gemm2(
    const short* __restrict__ C1, const double* __restrict__ Ac, const double* __restrict__ Bc,
    const int8_t* __restrict__ W2q, int* __restrict__ C2, int* __restrict__ sum2p,
    ull* __restrict__ sq2p) {
  __shared__ double AcS[N1];
  __shared__ double BcS[N1];
  __shared__ int8_t W2s[16 * W2S];
  __shared__ int cS[16];
  __shared__ int cQ[16];
  const int t = threadIdx.x;
  for (int i = t; i < N1; i += 256) {
    AcS[i] = Ac[i];
    BcS[i] = Bc[i];
  }
  for (int i = t; i < 1024; i += 256) {  // 16KB of W2 as 16B chunks
    int r = i >> 6, c16 = (i & 63) * 16;
    *(int4*)&W2s[r * W2S + c16] = *(const int4*)&W2q[r * N1 + c16];
  }
  if (t < 16) {
    cS[t] = 0;
    cQ[t] = 0;
  }
  __syncthreads();

  const int lane = t & 63, wave = t >> 6;
  const int m = lane & 15, kc = lane >> 4;
  const int tile = blockIdx.x * 4 + wave;  // 0..1023
  const int rowBase = tile * 16;
  const short* arow = &C1[(size_t)(rowBase + m) * N1];

  i32x4 acc = {0, 0, 0, 0};
#pragma unroll
  for (int kt = 0; kt < 16; ++kt) {
    const int k0 = kt * 64 + kc * 16;
    s16x8 v0 = *(const s16x8*)&arow[k0];
    s16x8 v1 = *(const s16x8*)&arow[k0 + 8];
    union {
      i32x4 v;
      int8_t b[16];
    } afr;
#pragma unroll
    for (int j = 0; j < 8; ++j) {
      double z = (double)v0[j] * AcS[k0 + j] + BcS[k0 + j];
      double qq = rint(z);
      qq = qq < -1.0 ? -1.0 : (qq > 1.0 ? 1.0 : qq);
      afr.b[j] = (int8_t)qq;
    }
#pragma unroll
    for (int j = 0; j < 8; ++j) {
      double z = (double)v1[j] * AcS[k0 + 8 + j] + BcS[k0 + 8 + j];
      double qq = rint(z);
      qq = qq < -1.0 ? -1.0 : (qq > 1.0 ? 1.0 : qq);
      afr.b[8 + j] = (int8_t)qq;
    }
    i32x4 bfr = *(const i32x4*)&W2s[m * W2S + k0];
    acc = __builtin_amdgcn_mfma_i32_16x16x64_i8(afr.v, bfr, acc, 0, 0, 0);
  }

  // C/D layout: col = lane&15, row = (lane>>4)*4 + reg
  const int col = m;
#pragma unroll
  for (int rg = 0; rg < 4; ++rg) C2[(rowBase + kc * 4 + rg) * 16 + col] = acc[rg];
  if (col < N2) {
    int s = 0, sq = 0;
#pragma unroll
    for (int rg = 0; rg < 4; ++rg) {
      int v = acc[rg];
      s += v;
      sq += v * v;
    }
    atomicAdd(&cS[col], s);
    atomicAdd(&cQ[col], sq);
  }
  __syncthreads();
  if (t < N2) {
    atomicAdd(&sum2p[t * 16], cS[t]);
    atomicAdd(&sq2p[t * 8], (ull)(unsigned)cQ[t]);
  }
}

// K7: t2 = ternary(batchnorm2(C2)) + global sum/sumsq of t2 (exact int).
__global__ __launch_bounds__(256) void k7_bn2q(const int* __restrict__ C2,
                                               const int* __restrict__ sum2p,
                                               const ull* __restrict__ sq2p,
                                               const float* __restrict__ g2,
                                               const float* __restrict__ b2,
                                               int8_t* __restrict__ t2, int* __restrict__ gsum,
                                               int* __restrict__ gsq) {
  int s = 0, sq = 0;
  for (int id = blockIdx.x * 256 + threadIdx.x; id < NTOT; id += gridDim.x * 256) {
    int r = id / N2, c = id - r * N2;
    int v = C2[r * 16 + c];
    double mean = (double)sum2p[c * 16] / 16384.0;
    double var = (double)sq2p[c * 8] / 16384.0 - mean * mean;
    double z = ((double)v - mean) / sqrt(var + 1e-5) * (double)g2[c] + (double)b2[c];
    double qq = rint(z);
    qq = qq < -1.0 ? -1.0 : (qq > 1.0 ? 1.0 : qq);
    int ti = (int)qq;
    t2[id] = (int8_t)ti;
    s += ti;
    sq += ti * ti;
  }
#pragma unroll
  for (int off = 32; off > 0; off >>= 1) {
    s += __shfl_xor(s, off, 64);
    sq += __shfl_xor(sq, off, 64);
  }
  __shared__ int bs, bq;
  if (threadIdx.x == 0) {
    bs = 0;
    bq = 0;
  }
  __syncthreads();
  if ((threadIdx.x & 63) == 0) {
    atomicAdd(&bs, s);
    atomicAdd(&bq, sq);
  }
  __syncthreads();
  if (threadIdx.x == 0) {
    atomicAdd(gsum, bs);
    atomicAdd(gsq, bq);
  }
}

// K9: out = tensornorm(t2)  (unbiased var, eps=1e-4)
__global__ void k9_out(const int8_t* __restrict__ t2, const int* __restrict__ gsum,
                       const int* __restrict__ gsq, const float* __restrict__ tn_w,
                       const float* __restrict__ tn_b, float* __restrict__ out) {
  int id = blockIdx.x * 256 + threadIdx.x;
  double n = (double)NTOT;
  double sm = (double)*gsum;
  double mean = sm / n;
  double var = ((double)*gsq - sm * sm / n) / (n - 1.0);
  double alpha = (double)tn_w[0] / sqrt(var + 1e-4);
  out[id] = (float)(((double)t2[id] - mean) * alpha + (double)tn_b[0]);
}

extern "C" void kernel_launch(void* const* d_in, const int* in_sizes, int n_in, void* d_out,
                              int out_size, void* d_ws, size_t ws_size, hipStream_t stream) {
  const float* x = (const float*)d_in[0];
  const float* W1 = (const float*)d_in[1];
  const float* g1 = (const float*)d_in[2];
  const float* b1 = (const float*)d_in[3];
  const float* W2 = (const float*)d_in[4];
  const float* g2 = (const float*)d_in[5];
  const float* b2 = (const float*)d_in[6];
  const float* tnw = (const float*)d_in[7];
  const float* tnb = (const float*)d_in[8];

  char* ws = (char*)d_ws;
  int8_t* Aq = (int8_t*)(ws + OFF_AQ);
  int8_t* W1q = (int8_t*)(ws + OFF_W1Q);
  int8_t* W2q = (int8_t*)(ws + OFF_W2Q);
  short* C1 = (short*)(ws + OFF_C1);
  int* statsZ = (int*)(ws + OFF_STATS);
  int* colsum = (int*)(ws + OFF_STATS);
  ull* colsq = (ull*)(ws + OFF_STATS + 4096);
  int* sum2p = (int*)(ws + OFF_STATS + 12288);
  ull* sq2p = (ull*)(ws + OFF_STATS + 13312);
  int* gsum = (int*)(ws + OFF_STATS + 14336);
  int* gsq = (int*)(ws + OFF_STATS + 14400);
  double* Ac = (double*)(ws + OFF_BN1);
  double* Bc = (double*)(ws + OFF_BN1 + 8192);
  int* C2 = (int*)(ws + OFF_C2);
  int8_t* t2 = (int8_t*)(ws + OFF_T2);

  const int totalT = BB * KP / 16 + N1 * KP / 16 + N2 * N1 / 16;  // 905856
  k0_quant<<<(totalT + 255) / 256, 256, 0, stream>>>(x, W1, W2, Aq, W1q, W2q, statsZ);
  k1_gemm1<<<dim3(8, 128), 256, 0, stream>>>(Aq, W1q, C1, colsum, colsq);
  k3_bn1<<<4, 256, 0, stream>>>(colsum, colsq, g1, b1, Ac, Bc);
  k45_bnq_gemm2<<<256, 256, 0, stream>>>(C1, Ac, Bc, W2q, C2, sum2p, sq2p);
  k7_bn2q<<<160, 256, 0, stream>>>(C2, sum2p, sq2p, g2, b2, t2, gsum, gsq);
  k9_out<<<NTOT / 256, 256, 0, stream>>>(t2, gsum, gsq, tnw, tnb, (float*)d_out);
}

// Round 5
// 153.779 us; speedup vs baseline: 1.6024x; 1.0264x over previous
//
#include <hip/hip_runtime.h>
#include <stdint.h>

typedef int i32x4 __attribute__((ext_vector_type(4)));
typedef short s16x8 __attribute__((ext_vector_type(8)));
typedef unsigned long long ull;

#define BB 16384
#define KD 784
#define KP 896  // padded to multiple of 128 (BK=128)
#define N1 1024
#define N2 10
#define NTOT (BB * N2)  // 163840

// ---- workspace layout (bytes) ----
#define OFF_AQ 0ULL
#define SZ_AQ (14680064ULL)  // 16384*896 i8
#define OFF_W1Q (OFF_AQ + SZ_AQ)
#define SZ_W1Q (917504ULL)  // 1024*896 i8
#define OFF_W2Q (OFF_W1Q + SZ_W1Q)
#define SZ_W2Q (16384ULL)  // 16*1024 i8 (rows 10..15 poison; masked downstream)
#define OFF_C1 (OFF_W2Q + SZ_W2Q)
#define SZ_C1 (33554432ULL)  // 16384*1024 i16
#define OFF_STATS (OFF_C1 + SZ_C1)
#define SZ_STATS (16384ULL)
// stats sublayout (bytes): colsum int[1024] @0; colsq ull[1024] @4096;
//   sum2p int stride 16 ints (64B), 16 entries @12288;
//   sq2p  ull stride 8 ulls (64B), 16 entries @13312;
//   gsum int @14336; gsq int @14400  (separate cache lines)
#define OFF_C2 (OFF_STATS + SZ_STATS)
#define SZ_C2 (1048576ULL)  // 16384*16 int (padded cols)
#define OFF_T2 (OFF_C2 + SZ_C2)
#define SZ_T2 (163840ULL)  // i8

__device__ __forceinline__ void async16(const void* g, void* l) {
  __builtin_amdgcn_global_load_lds((__attribute__((address_space(1))) void*)(void*)(g),
                                   (__attribute__((address_space(3))) void*)(l), 16, 0, 0);
}

__device__ __forceinline__ int8_t ternq(float v) {
  float q = rintf(v);
  return q > 0.5f ? 1 : (q < -0.5f ? -1 : 0);
}

// K0: quantize x -> Aq (i8, K padded to 896), W1 -> W1q, W2 -> W2q; zero stats region.
__global__ void k0_quant(const float* __restrict__ x, const float* __restrict__ W1,
                         const float* __restrict__ W2, int8_t* __restrict__ Aq,
                         int8_t* __restrict__ W1q, int8_t* __restrict__ W2q,
                         int* __restrict__ stats) {
  const int TA = BB * KP / 16;  // 917504
  const int TW = N1 * KP / 16;  // 57344
  const int T2 = N2 * N1 / 16;  // 640
  int tid = blockIdx.x * 256 + threadIdx.x;
  if (tid < 4096) stats[tid] = 0;  // 16KB stats zeroed (runs before k1 in stream order)
  union {
    int4 v;
    int8_t b[16];
  } o;
  o.v = make_int4(0, 0, 0, 0);
  if (tid < TA) {
    int base = tid * 16;
    int r = base / KP, k = base - r * KP;
    if (k < KD) {
      const float4* xp = (const float4*)&x[r * KD + k];
#pragma unroll
      for (int g = 0; g < 4; ++g) {
        float4 f = xp[g];
        o.b[g * 4 + 0] = ternq(2.0f * f.x - 1.0f);
        o.b[g * 4 + 1] = ternq(2.0f * f.y - 1.0f);
        o.b[g * 4 + 2] = ternq(2.0f * f.z - 1.0f);
        o.b[g * 4 + 3] = ternq(2.0f * f.w - 1.0f);
      }
    }
    *(int4*)&Aq[base] = o.v;
  } else if (tid < TA + TW) {
    int base = (tid - TA) * 16;
    int r = base / KP, k = base - r * KP;
    if (k < KD) {
      const float4* wp = (const float4*)&W1[r * KD + k];
#pragma unroll
      for (int g = 0; g < 4; ++g) {
        float4 f = wp[g];
        o.b[g * 4 + 0] = ternq(f.x);
        o.b[g * 4 + 1] = ternq(f.y);
        o.b[g * 4 + 2] = ternq(f.z);
        o.b[g * 4 + 3] = ternq(f.w);
      }
    }
    *(int4*)&W1q[base] = o.v;
  } else if (tid < TA + TW + T2) {
    int base = (tid - TA - TW) * 16;
    const float4* wp = (const float4*)&W2[base];
#pragma unroll
    for (int g = 0; g < 4; ++g) {
      float4 f = wp[g];
      o.b[g * 4 + 0] = ternq(f.x);
      o.b[g * 4 + 1] = ternq(f.y);
      o.b[g * 4 + 2] = ternq(f.z);
      o.b[g * 4 + 3] = ternq(f.w);
    }
    *(int4*)&W2q[base] = o.v;
  }
}

// K1: C1 = Aq @ W1q^T (128x128 tile, BK=128, i8 MFMA 16x16x64) + fused col stats.
// 7 K-iters (vs 13 at BK=64): half the barrier drains, 32 MFMA/barrier.
// LDS row = 128B (32 banks); granule swizzle g^=(row&7) -> fragment reads uniform 2-way.
__global__ __launch_bounds__(256, 3) void k1_gemm1(const int8_t* __restrict__ Aq,
                                                   const int8_t* __restrict__ W1q,
                                                   short* __restrict__ C1,
                                                   int* __restrict__ colsum,
                                                   ull* __restrict__ colsq) {
  __shared__ int8_t As[128 * 128];
  __shared__ int8_t Bs[128 * 128];
  __shared__ int cS[128];
  __shared__ int cQ[128];
  const int t = threadIdx.x;
  const int lane = t & 63, wave = t >> 6;
  const int wr = wave >> 1, wc = wave & 1;
  const int rowBase = blockIdx.y * 128, colBase = blockIdx.x * 128;
  if (t < 128) {
    cS[t] = 0;
    cQ[t] = 0;
  }

  i32x4 acc[4][4] = {};
  const int m = lane & 15, kc = lane >> 4;

  // staging chunk descriptors: chunk c = t + 256*s, s=0..3; row=c>>3, pos=c&7,
  // logical granule g = pos ^ (row&7); LDS dst c*16 is lane-contiguous per wave.
  int srow[4], sgo[4];
#pragma unroll
  for (int s = 0; s < 4; ++s) {
    int c = t + 256 * s;
    srow[s] = c >> 3;
    sgo[s] = ((c & 7) ^ (srow[s] & 7)) * 16;
  }

  for (int kt = 0; kt < 7; ++kt) {
    __syncthreads();
    const int kb = kt * 128;
#pragma unroll
    for (int s = 0; s < 4; ++s) {
      int c = t + 256 * s;
      async16(&Aq[(size_t)(rowBase + srow[s]) * KP + kb + sgo[s]], &As[c * 16]);
      async16(&W1q[(size_t)(colBase + srow[s]) * KP + kb + sgo[s]], &Bs[c * 16]);
    }
    __syncthreads();
#pragma unroll
    for (int h = 0; h < 2; ++h) {
      i32x4 av[4], bv[4];
#pragma unroll
      for (int i = 0; i < 4; ++i) {
        int row = 64 * wr + 16 * i + m;
        av[i] = *(const i32x4*)&As[row * 128 + (((4 * h + kc) ^ (row & 7)) * 16)];
      }
#pragma unroll
      for (int j = 0; j < 4; ++j) {
        int row = 64 * wc + 16 * j + m;
        bv[j] = *(const i32x4*)&Bs[row * 128 + (((4 * h + kc) ^ (row & 7)) * 16)];
      }
#pragma unroll
      for (int i = 0; i < 4; ++i)
#pragma unroll
        for (int j = 0; j < 4; ++j)
          acc[i][j] = __builtin_amdgcn_mfma_i32_16x16x64_i8(av[i], bv[j], acc[i][j], 0, 0, 0);
    }
  }

  // epilogue: store C1 (i16) + per-column partial sum/sumsq into LDS
  const int q = lane >> 4, cl = lane & 15;
#pragma unroll
  for (int j = 0; j < 4; ++j) {
    const int colLoc = 64 * wc + 16 * j + cl;
    const int col = colBase + colLoc;
    int s = 0, sq = 0;
#pragma unroll
    for (int i = 0; i < 4; ++i) {
#pragma unroll
      for (int rg = 0; rg < 4; ++rg) {
        int v = acc[i][j][rg];
        int row = rowBase + 64 * wr + 16 * i + q * 4 + rg;
        C1[(size_t)row * N1 + col] = (short)v;
        s += v;
        sq += v * v;  // <= 128 * 784^2 = 7.9e7, fits int32 per block
      }
    }
    atomicAdd(&cS[colLoc], s);
    atomicAdd(&cQ[colLoc], sq);
  }
  __syncthreads();
  if (t < 128) {
    atomicAdd(&colsum[colBase + t], cS[t]);
    atomicAdd(&colsq[colBase + t], (ull)(unsigned)cQ[t]);
  }
}

// K45: fused BN1-constants + BN1-ternary + GEMM2 (i8 MFMA, wave=16x16 tile, K=1024)
// + C2 col stats. Ac/Bc computed in-block from colsum/colsq (k3 eliminated).
#define W2S 1040  // LDS row stride for W2 (2-way bank alias = free)
__global__ __launch_bounds__(256) void k45_bnq_gemm2(
    const short* __restrict__ C1, const int* __restrict__ colsum, const ull* __restrict__ colsq,
    const float* __restrict__ g1, const float* __restrict__ b1, const int8_t* __restrict__ W2q,
    int* __restrict__ C2, int* __restrict__ sum2p, ull* __restrict__ sq2p) {
  __shared__ double AcS[N1];
  __shared__ double BcS[N1];
  __shared__ int8_t W2s[16 * W2S];
  __shared__ int cS[16];
  __shared__ int cQ[16];
  const int t = threadIdx.x;
  for (int i = t; i < N1; i += 256) {
    double mean = (double)colsum[i] / 16384.0;
    double var = (double)colsq[i] / 16384.0 - mean * mean;
    double a = (double)g1[i] / sqrt(var + 1e-5);
    AcS[i] = a;
    BcS[i] = (double)b1[i] - mean * a;
  }
  for (int i = t; i < 1024; i += 256) {  // 16KB of W2 as 16B chunks
    int r = i >> 6, c16 = (i & 63) * 16;
    *(int4*)&W2s[r * W2S + c16] = *(const int4*)&W2q[r * N1 + c16];
  }
  if (t < 16) {
    cS[t] = 0;
    cQ[t] = 0;
  }
  __syncthreads();

  const int lane = t & 63, wave = t >> 6;
  const int m = lane & 15, kc = lane >> 4;
  const int tile = blockIdx.x * 4 + wave;  // 0..1023
  const int rowBase = tile * 16;
  const short* arow = &C1[(size_t)(rowBase + m) * N1];

  i32x4 acc = {0, 0, 0, 0};
#pragma unroll
  for (int kt = 0; kt < 16; ++kt) {
    const int k0 = kt * 64 + kc * 16;
    s16x8 v0 = *(const s16x8*)&arow[k0];
    s16x8 v1 = *(const s16x8*)&arow[k0 + 8];
    union {
      i32x4 v;
      int8_t b[16];
    } afr;
#pragma unroll
    for (int j = 0; j < 8; ++j) {
      double z = (double)v0[j] * AcS[k0 + j] + BcS[k0 + j];
      double qq = rint(z);
      qq = qq < -1.0 ? -1.0 : (qq > 1.0 ? 1.0 : qq);
      afr.b[j] = (int8_t)qq;
    }
#pragma unroll
    for (int j = 0; j < 8; ++j) {
      double z = (double)v1[j] * AcS[k0 + 8 + j] + BcS[k0 + 8 + j];
      double qq = rint(z);
      qq = qq < -1.0 ? -1.0 : (qq > 1.0 ? 1.0 : qq);
      afr.b[8 + j] = (int8_t)qq;
    }
    i32x4 bfr = *(const i32x4*)&W2s[m * W2S + k0];
    acc = __builtin_amdgcn_mfma_i32_16x16x64_i8(afr.v, bfr, acc, 0, 0, 0);
  }

  // C/D layout: col = lane&15, row = (lane>>4)*4 + reg
  const int col = m;
#pragma unroll
  for (int rg = 0; rg < 4; ++rg) C2[(rowBase + kc * 4 + rg) * 16 + col] = acc[rg];
  if (col < N2) {
    int s = 0, sq = 0;
#pragma unroll
    for (int rg = 0; rg < 4; ++rg) {
      int v = acc[rg];
      s += v;
      sq += v * v;
    }
    atomicAdd(&cS[col], s);
    atomicAdd(&cQ[col], sq);
  }
  __syncthreads();
  if (t < N2) {
    atomicAdd(&sum2p[t * 16], cS[t]);
    atomicAdd(&sq2p[t * 8], (ull)(unsigned)cQ[t]);
  }
}

// K7: t2 = ternary(batchnorm2(C2)) + global sum/sumsq of t2 (exact int).
__global__ __launch_bounds__(256) void k7_bn2q(const int* __restrict__ C2,
                                               const int* __restrict__ sum2p,
                                               const ull* __restrict__ sq2p,
                                               const float* __restrict__ g2,
                                               const float* __restrict__ b2,
                                               int8_t* __restrict__ t2, int* __restrict__ gsum,
                                               int* __restrict__ gsq) {
  int s = 0, sq = 0;
  for (int id = blockIdx.x * 256 + threadIdx.x; id < NTOT; id += gridDim.x * 256) {
    int r = id / N2, c = id - r * N2;
    int v = C2[r * 16 + c];
    double mean = (double)sum2p[c * 16] / 16384.0;
    double var = (double)sq2p[c * 8] / 16384.0 - mean * mean;
    double z = ((double)v - mean) / sqrt(var + 1e-5) * (double)g2[c] + (double)b2[c];
    double qq = rint(z);
    qq = qq < -1.0 ? -1.0 : (qq > 1.0 ? 1.0 : qq);
    int ti = (int)qq;
    t2[id] = (int8_t)ti;
    s += ti;
    sq += ti * ti;
  }
#pragma unroll
  for (int off = 32; off > 0; off >>= 1) {
    s += __shfl_xor(s, off, 64);
    sq += __shfl_xor(sq, off, 64);
  }
  __shared__ int bs, bq;
  if (threadIdx.x == 0) {
    bs = 0;
    bq = 0;
  }
  __syncthreads();
  if ((threadIdx.x & 63) == 0) {
    atomicAdd(&bs, s);
    atomicAdd(&bq, sq);
  }
  __syncthreads();
  if (threadIdx.x == 0) {
    atomicAdd(gsum, bs);
    atomicAdd(gsq, bq);
  }
}

// K9: out = tensornorm(t2)  (unbiased var, eps=1e-4)
__global__ void k9_out(const int8_t* __restrict__ t2, const int* __restrict__ gsum,
                       const int* __restrict__ gsq, const float* __restrict__ tn_w,
                       const float* __restrict__ tn_b, float* __restrict__ out) {
  int id = blockIdx.x * 256 + threadIdx.x;
  double n = (double)NTOT;
  double sm = (double)*gsum;
  double mean = sm / n;
  double var = ((double)*gsq - sm * sm / n) / (n - 1.0);
  double alpha = (double)tn_w[0] / sqrt(var + 1e-4);
  out[id] = (float)(((double)t2[id] - mean) * alpha + (double)tn_b[0]);
}

extern "C" void kernel_launch(void* const* d_in, const int* in_sizes, int n_in, void* d_out,
                              int out_size, void* d_ws, size_t ws_size, hipStream_t stream) {
  const float* x = (const float*)d_in[0];
  const float* W1 = (const float*)d_in[1];
  const float* g1 = (const float*)d_in[2];
  const float* b1 = (const float*)d_in[3];
  const float* W2 = (const float*)d_in[4];
  const float* g2 = (const float*)d_in[5];
  const float* b2 = (const float*)d_in[6];
  const float* tnw = (const float*)d_in[7];
  const float* tnb = (const float*)d_in[8];

  char* ws = (char*)d_ws;
  int8_t* Aq = (int8_t*)(ws + OFF_AQ);
  int8_t* W1q = (int8_t*)(ws + OFF_W1Q);
  int8_t* W2q = (int8_t*)(ws + OFF_W2Q);
  short* C1 = (short*)(ws + OFF_C1);
  int* statsZ = (int*)(ws + OFF_STATS);
  int* colsum = (int*)(ws + OFF_STATS);
  ull* colsq = (ull*)(ws + OFF_STATS + 4096);
  int* sum2p = (int*)(ws + OFF_STATS + 12288);
  ull* sq2p = (ull*)(ws + OFF_STATS + 13312);
  int* gsum = (int*)(ws + OFF_STATS + 14336);
  int* gsq = (int*)(ws + OFF_STATS + 14400);
  int* C2 = (int*)(ws + OFF_C2);
  int8_t* t2 = (int8_t*)(ws + OFF_T2);

  const int totalT = BB * KP / 16 + N1 * KP / 16 + N2 * N1 / 16;  // 975488
  k0_quant<<<(totalT + 255) / 256, 256, 0, stream>>>(x, W1, W2, Aq, W1q, W2q, statsZ);
  k1_gemm1<<<dim3(8, 128), 256, 0, stream>>>(Aq, W1q, C1, colsum, colsq);
  k45_bnq_gemm2<<<256, 256, 0, stream>>>(C1, colsum, colsq, g1, b1, W2q, C2, sum2p, sq2p);
  k7_bn2q<<<160, 256, 0, stream>>>(C2, sum2p, sq2p, g2, b2, t2, gsum, gsq);
  k9_out<<<NTOT / 256, 256, 0, stream>>>(t2, gsum, gsq, tnw, tnb, (float*)d_out);
}

// Round 6
// 151.821 us; speedup vs baseline: 1.6231x; 1.0129x over previous
//
#include <hip/hip_runtime.h>
#include <stdint.h>

typedef int i32x4 __attribute__((ext_vector_type(4)));
typedef short s16x8 __attribute__((ext_vector_type(8)));
typedef unsigned long long ull;

#define BB 16384
#define KD 784
#define KP 896  // padded to multiple of 128 (BK=128)
#define N1 1024
#define N2 10
#define NTOT (BB * N2)  // 163840

// ---- workspace layout (bytes) ----
#define OFF_AQ 0ULL
#define SZ_AQ (14680064ULL)  // 16384*896 i8
#define OFF_W1Q (OFF_AQ + SZ_AQ)
#define SZ_W1Q (917504ULL)  // 1024*896 i8
#define OFF_W2Q (OFF_W1Q + SZ_W1Q)
#define SZ_W2Q (16384ULL)  // 16*1024 i8 (rows 10..15 poison; masked downstream)
#define OFF_C1 (OFF_W2Q + SZ_W2Q)
#define SZ_C1 (33554432ULL)  // 16384*1024 i16
#define OFF_STATS (OFF_C1 + SZ_C1)
#define SZ_STATS (16384ULL)
// stats sublayout (bytes): colsum int[1024] @0; colsq ull[1024] @4096;
//   sum2p int stride 16 ints (64B), 16 entries @12288;
//   sq2p  ull stride 8 ulls (64B), 16 entries @13312;
//   gsum int @14336; gsq int @14400  (separate cache lines)
#define OFF_C2 (OFF_STATS + SZ_STATS)
#define SZ_C2 (524288ULL)  // 16384*16 i16 (padded cols)
#define OFF_T2 (OFF_C2 + SZ_C2)
#define SZ_T2 (163840ULL)  // i8

__device__ __forceinline__ void async16(const void* g, void* l) {
  __builtin_amdgcn_global_load_lds((__attribute__((address_space(1))) void*)(void*)(g),
                                   (__attribute__((address_space(3))) void*)(l), 16, 0, 0);
}

__device__ __forceinline__ int8_t ternq(float v) {
  float q = rintf(v);
  return q > 0.5f ? 1 : (q < -0.5f ? -1 : 0);
}

// K0: quantize x -> Aq (i8, K padded to 896), W1 -> W1q, W2 -> W2q; zero stats region.
__global__ void k0_quant(const float* __restrict__ x, const float* __restrict__ W1,
                         const float* __restrict__ W2, int8_t* __restrict__ Aq,
                         int8_t* __restrict__ W1q, int8_t* __restrict__ W2q,
                         int* __restrict__ stats) {
  const int TA = BB * KP / 16;  // 917504
  const int TW = N1 * KP / 16;  // 57344
  const int T2 = N2 * N1 / 16;  // 640
  int tid = blockIdx.x * 256 + threadIdx.x;
  if (tid < 4096) stats[tid] = 0;  // 16KB stats zeroed (runs before k1 in stream order)
  union {
    int4 v;
    int8_t b[16];
  } o;
  o.v = make_int4(0, 0, 0, 0);
  if (tid < TA) {
    int base = tid * 16;
    int r = base / KP, k = base - r * KP;
    if (k < KD) {
      const float4* xp = (const float4*)&x[r * KD + k];
#pragma unroll
      for (int g = 0; g < 4; ++g) {
        float4 f = xp[g];
        o.b[g * 4 + 0] = ternq(2.0f * f.x - 1.0f);
        o.b[g * 4 + 1] = ternq(2.0f * f.y - 1.0f);
        o.b[g * 4 + 2] = ternq(2.0f * f.z - 1.0f);
        o.b[g * 4 + 3] = ternq(2.0f * f.w - 1.0f);
      }
    }
    *(int4*)&Aq[base] = o.v;
  } else if (tid < TA + TW) {
    int base = (tid - TA) * 16;
    int r = base / KP, k = base - r * KP;
    if (k < KD) {
      const float4* wp = (const float4*)&W1[r * KD + k];
#pragma unroll
      for (int g = 0; g < 4; ++g) {
        float4 f = wp[g];
        o.b[g * 4 + 0] = ternq(f.x);
        o.b[g * 4 + 1] = ternq(f.y);
        o.b[g * 4 + 2] = ternq(f.z);
        o.b[g * 4 + 3] = ternq(f.w);
      }
    }
    *(int4*)&W1q[base] = o.v;
  } else if (tid < TA + TW + T2) {
    int base = (tid - TA - TW) * 16;
    const float4* wp = (const float4*)&W2[base];
#pragma unroll
    for (int g = 0; g < 4; ++g) {
      float4 f = wp[g];
      o.b[g * 4 + 0] = ternq(f.x);
      o.b[g * 4 + 1] = ternq(f.y);
      o.b[g * 4 + 2] = ternq(f.z);
      o.b[g * 4 + 3] = ternq(f.w);
    }
    *(int4*)&W2q[base] = o.v;
  }
}

// K1: C1 = Aq @ W1q^T (128x128 tile, BK=128, i8 MFMA 16x16x64) + fused col stats.
// 7 K-iters, 32 MFMA/barrier. launch_bounds(256,4): 4 blocks/CU (132KB LDS, VGPR<=128,
// acc in AGPRs) for more wave-level overlap of the barrier drain.
__global__ __launch_bounds__(256, 4) void k1_gemm1(const int8_t* __restrict__ Aq,
                                                   const int8_t* __restrict__ W1q,
                                                   short* __restrict__ C1,
                                                   int* __restrict__ colsum,
                                                   ull* __restrict__ colsq) {
  __shared__ int8_t As[128 * 128];
  __shared__ int8_t Bs[128 * 128];
  __shared__ int cS[128];
  __shared__ int cQ[128];
  const int t = threadIdx.x;
  const int lane = t & 63, wave = t >> 6;
  const int wr = wave >> 1, wc = wave & 1;
  const int rowBase = blockIdx.y * 128, colBase = blockIdx.x * 128;
  if (t < 128) {
    cS[t] = 0;
    cQ[t] = 0;
  }

  i32x4 acc[4][4] = {};
  const int m = lane & 15, kc = lane >> 4;

  // staging: chunk c = t + 256*s, s=0..3; row=c>>3, pos=c&7, granule g = pos ^ (row&7)
  int srow[4], sgo[4];
#pragma unroll
  for (int s = 0; s < 4; ++s) {
    int c = t + 256 * s;
    srow[s] = c >> 3;
    sgo[s] = ((c & 7) ^ (srow[s] & 7)) * 16;
  }

  for (int kt = 0; kt < 7; ++kt) {
    __syncthreads();
    const int kb = kt * 128;
#pragma unroll
    for (int s = 0; s < 4; ++s) {
      int c = t + 256 * s;
      async16(&Aq[(size_t)(rowBase + srow[s]) * KP + kb + sgo[s]], &As[c * 16]);
      async16(&W1q[(size_t)(colBase + srow[s]) * KP + kb + sgo[s]], &Bs[c * 16]);
    }
    __syncthreads();
#pragma unroll
    for (int h = 0; h < 2; ++h) {
      i32x4 av[4], bv[4];
#pragma unroll
      for (int i = 0; i < 4; ++i) {
        int row = 64 * wr + 16 * i + m;
        av[i] = *(const i32x4*)&As[row * 128 + (((4 * h + kc) ^ (row & 7)) * 16)];
      }
#pragma unroll
      for (int j = 0; j < 4; ++j) {
        int row = 64 * wc + 16 * j + m;
        bv[j] = *(const i32x4*)&Bs[row * 128 + (((4 * h + kc) ^ (row & 7)) * 16)];
      }
#pragma unroll
      for (int i = 0; i < 4; ++i)
#pragma unroll
        for (int j = 0; j < 4; ++j)
          acc[i][j] = __builtin_amdgcn_mfma_i32_16x16x64_i8(av[i], bv[j], acc[i][j], 0, 0, 0);
    }
  }

  // epilogue: store C1 (i16) + per-column partial sum/sumsq into LDS
  const int q = lane >> 4, cl = lane & 15;
#pragma unroll
  for (int j = 0; j < 4; ++j) {
    const int colLoc = 64 * wc + 16 * j + cl;
    const int col = colBase + colLoc;
    int s = 0, sq = 0;
#pragma unroll
    for (int i = 0; i < 4; ++i) {
#pragma unroll
      for (int rg = 0; rg < 4; ++rg) {
        int v = acc[i][j][rg];
        int row = rowBase + 64 * wr + 16 * i + q * 4 + rg;
        C1[(size_t)row * N1 + col] = (short)v;
        s += v;
        sq += v * v;  // <= 128 * 784^2 = 7.9e7, fits int32 per block
      }
    }
    atomicAdd(&cS[colLoc], s);
    atomicAdd(&cQ[colLoc], sq);
  }
  __syncthreads();
  if (t < 128) {
    atomicAdd(&colsum[colBase + t], cS[t]);
    atomicAdd(&colsq[colBase + t], (ull)(unsigned)cQ[t]);
  }
}

// Per-column integer ternary thresholds for z = fma(v,a,b):
// out = (w>=hi) - (w<=lo), w = sgn*v. Exact local search on the fma-evaluated boundary
// (HIP contracts v*a+b to fma, so decisions are identical to the passing double path).
__device__ __forceinline__ void mk_thr(double a, double b, int& hi, int& lo, int8_t& sgn) {
  sgn = 1;
  if (a < 0.0) {
    a = -a;
    sgn = -1;  // z = (-v)*(-a) + b : monotone increasing in w=-v
  }
  if (a == 0.0) {
    double q = rint(b);
    if (q > 0.5) {
      hi = -1500;
      lo = -2000;
    } else if (q < -0.5) {
      hi = 2000;
      lo = 1500;
    } else {
      hi = 1500;
      lo = -1500;
    }
    return;
  }
  double g = (0.5 - b) / a;
  g = g > 1e6 ? 1e6 : (g < -1e6 ? -1e6 : g);
  if (g != g) g = 0.0;
  int c0 = (int)floor(g);
  c0 = c0 < -1400 ? -1400 : (c0 > 1400 ? 1400 : c0);
  for (int it = 0; it < 6 && fma((double)(c0 - 1), a, b) > 0.5; ++it) --c0;
  for (int it = 0; it < 6 && fma((double)c0, a, b) <= 0.5; ++it) ++c0;
  hi = c0 < -1500 ? -1500 : (c0 > 1500 ? 1500 : c0);
  double g2 = (-0.5 - b) / a;
  g2 = g2 > 1e6 ? 1e6 : (g2 < -1e6 ? -1e6 : g2);
  if (g2 != g2) g2 = 0.0;
  int c1 = (int)ceil(g2);
  c1 = c1 < -1400 ? -1400 : (c1 > 1400 ? 1400 : c1);
  for (int it = 0; it < 6 && fma((double)(c1 + 1), a, b) < -0.5; ++it) ++c1;
  for (int it = 0; it < 6 && fma((double)c1, a, b) >= -0.5; ++it) --c1;
  lo = c1 < -1500 ? -1500 : (c1 > 1500 ? 1500 : c1);
}

// K45: fused BN1-ternary (integer thresholds) + GEMM2 (i8 MFMA, wave=16x16 tile, K=1024)
// + C2 col stats. Thresholds computed in-block from colsum/colsq.
#define W2S 1040  // LDS row stride for W2 (2-way bank alias = free)
__global__ __launch_bounds__(256) void k45_bnq_gemm2(
    const short* __restrict__ C1, const int* __restrict__ colsum, const ull* __restrict__ colsq,
    const float* __restrict__ g1, const float* __restrict__ b1, const int8_t* __restrict__ W2q,
    short* __restrict__ C2, int* __restrict__ sum2p, ull* __restrict__ sq2p) {
  __shared__ int tpkS[N1];     // (hi<<16) | (lo & 0xffff)
  __shared__ int8_t sgnS[N1];  // per-column sign fold
  __shared__ int8_t W2s[16 * W2S];
  __shared__ int cS[16];
  __shared__ int cQ[16];
  const int t = threadIdx.x;
  for (int i = t; i < N1; i += 256) {
    double mean = (double)colsum[i] / 16384.0;
    double var = (double)colsq[i] / 16384.0 - mean * mean;
    double a = (double)g1[i] / sqrt(var + 1e-5);
    double b = (double)b1[i] - mean * a;
    int hi, lo;
    int8_t sg;
    mk_thr(a, b, hi, lo, sg);
    tpkS[i] = (hi << 16) | (lo & 0xffff);
    sgnS[i] = sg;
  }
  for (int i = t; i < 1024; i += 256) {  // 16KB of W2 as 16B chunks
    int r = i >> 6, c16 = (i & 63) * 16;
    *(int4*)&W2s[r * W2S + c16] = *(const int4*)&W2q[r * N1 + c16];
  }
  if (t < 16) {
    cS[t] = 0;
    cQ[t] = 0;
  }
  __syncthreads();

  const int lane = t & 63, wave = t >> 6;
  const int m = lane & 15, kc = lane >> 4;
  const int tile = blockIdx.x * 4 + wave;  // 0..1023
  const int rowBase = tile * 16;
  const short* arow = &C1[(size_t)(rowBase + m) * N1];

  i32x4 acc = {0, 0, 0, 0};
#pragma unroll
  for (int kt = 0; kt < 16; ++kt) {
    const int k0 = kt * 64 + kc * 16;
    s16x8 v0 = *(const s16x8*)&arow[k0];
    s16x8 v1 = *(const s16x8*)&arow[k0 + 8];
    union {
      int4 v[4];
      int w[16];
    } tps;
    tps.v[0] = *(const int4*)&tpkS[k0];
    tps.v[1] = *(const int4*)&tpkS[k0 + 4];
    tps.v[2] = *(const int4*)&tpkS[k0 + 8];
    tps.v[3] = *(const int4*)&tpkS[k0 + 12];
    union {
      int4 v;
      int8_t b[16];
    } sg;
    sg.v = *(const int4*)&sgnS[k0];
    union {
      i32x4 v;
      int8_t b[16];
    } afr;
#pragma unroll
    for (int j = 0; j < 8; ++j) {
      int tp = tps.w[j];
      int hi = tp >> 16, lo = (short)(tp & 0xffff);
      int w = (int)v0[j] * (int)sg.b[j];
      afr.b[j] = (int8_t)((w >= hi) - (w <= lo));
    }
#pragma unroll
    for (int j = 0; j < 8; ++j) {
      int tp = tps.w[8 + j];
      int hi = tp >> 16, lo = (short)(tp & 0xffff);
      int w = (int)v1[j] * (int)sg.b[8 + j];
      afr.b[8 + j] = (int8_t)((w >= hi) - (w <= lo));
    }
    i32x4 bfr = *(const i32x4*)&W2s[m * W2S + k0];
    acc = __builtin_amdgcn_mfma_i32_16x16x64_i8(afr.v, bfr, acc, 0, 0, 0);
  }

  // C/D layout: col = lane&15, row = (lane>>4)*4 + reg
  const int col = m;
#pragma unroll
  for (int rg = 0; rg < 4; ++rg) C2[(rowBase + kc * 4 + rg) * 16 + col] = (short)acc[rg];
  if (col < N2) {
    int s = 0, sq = 0;
#pragma unroll
    for (int rg = 0; rg < 4; ++rg) {
      int v = acc[rg];
      s += v;
      sq += v * v;
    }
    atomicAdd(&cS[col], s);
    atomicAdd(&cQ[col], sq);
  }
  __syncthreads();
  if (t < N2) {
    atomicAdd(&sum2p[t * 16], cS[t]);
    atomicAdd(&sq2p[t * 8], (ull)(unsigned)cQ[t]);
  }
}

// K7: t2 = ternary(batchnorm2(C2)) + global sum/sumsq of t2 (exact int).
// Per-column mean/rs hoisted to LDS (same expression shape as before: (v-mean)/rs*g2+b2).
__global__ __launch_bounds__(256) void k7_bn2q(const short* __restrict__ C2,
                                               const int* __restrict__ sum2p,
                                               const ull* __restrict__ sq2p,
                                               const float* __restrict__ g2,
                                               const float* __restrict__ b2,
                                               int8_t* __restrict__ t2, int* __restrict__ gsum,
                                               int* __restrict__ gsq) {
  __shared__ double meanS[N2], rsS[N2];
  if (threadIdx.x < N2) {
    int c = threadIdx.x;
    double mean = (double)sum2p[c * 16] / 16384.0;
    double var = (double)sq2p[c * 8] / 16384.0 - mean * mean;
    meanS[c] = mean;
    rsS[c] = sqrt(var + 1e-5);
  }
  __syncthreads();
  int s = 0, sq = 0;
  for (int id = blockIdx.x * 256 + threadIdx.x; id < NTOT; id += gridDim.x * 256) {
    int r = id / N2, c = id - r * N2;
    int v = C2[r * 16 + c];
    double z = ((double)v - meanS[c]) / rsS[c] * (double)g2[c] + (double)b2[c];
    double qq = rint(z);
    qq = qq < -1.0 ? -1.0 : (qq > 1.0 ? 1.0 : qq);
    int ti = (int)qq;
    t2[id] = (int8_t)ti;
    s += ti;
    sq += ti * ti;
  }
#pragma unroll
  for (int off = 32; off > 0; off >>= 1) {
    s += __shfl_xor(s, off, 64);
    sq += __shfl_xor(sq, off, 64);
  }
  __shared__ int bs, bq;
  if (threadIdx.x == 0) {
    bs = 0;
    bq = 0;
  }
  __syncthreads();
  if ((threadIdx.x & 63) == 0) {
    atomicAdd(&bs, s);
    atomicAdd(&bq, sq);
  }
  __syncthreads();
  if (threadIdx.x == 0) {
    atomicAdd(gsum, bs);
    atomicAdd(gsq, bq);
  }
}

// K9: out = tensornorm(t2)  (unbiased var, eps=1e-4)
__global__ void k9_out(const int8_t* __restrict__ t2, const int* __restrict__ gsum,
                       const int* __restrict__ gsq, const float* __restrict__ tn_w,
                       const float* __restrict__ tn_b, float* __restrict__ out) {
  int id = blockIdx.x * 256 + threadIdx.x;
  double n = (double)NTOT;
  double sm = (double)*gsum;
  double mean = sm / n;
  double var = ((double)*gsq - sm * sm / n) / (n - 1.0);
  double alpha = (double)tn_w[0] / sqrt(var + 1e-4);
  out[id] = (float)(((double)t2[id] - mean) * alpha + (double)tn_b[0]);
}

extern "C" void kernel_launch(void* const* d_in, const int* in_sizes, int n_in, void* d_out,
                              int out_size, void* d_ws, size_t ws_size, hipStream_t stream) {
  const float* x = (const float*)d_in[0];
  const float* W1 = (const float*)d_in[1];
  const float* g1 = (const float*)d_in[2];
  const float* b1 = (const float*)d_in[3];
  const float* W2 = (const float*)d_in[4];
  const float* g2 = (const float*)d_in[5];
  const float* b2 = (const float*)d_in[6];
  const float* tnw = (const float*)d_in[7];
  const float* tnb = (const float*)d_in[8];

  char* ws = (char*)d_ws;
  int8_t* Aq = (int8_t*)(ws + OFF_AQ);
  int8_t* W1q = (int8_t*)(ws + OFF_W1Q);
  int8_t* W2q = (int8_t*)(ws + OFF_W2Q);
  short* C1 = (short*)(ws + OFF_C1);
  int* statsZ = (int*)(ws + OFF_STATS);
  int* colsum = (int*)(ws + OFF_STATS);
  ull* colsq = (ull*)(ws + OFF_STATS + 4096);
  int* sum2p = (int*)(ws + OFF_STATS + 12288);
  ull* sq2p = (ull*)(ws + OFF_STATS + 13312);
  int* gsum = (int*)(ws + OFF_STATS + 14336);
  int* gsq = (int*)(ws + OFF_STATS + 14400);
  short* C2 = (short*)(ws + OFF_C2);
  int8_t* t2 = (int8_t*)(ws + OFF_T2);

  const int totalT = BB * KP / 16 + N1 * KP / 16 + N2 * N1 / 16;  // 975488
  k0_quant<<<(totalT + 255) / 256, 256, 0, stream>>>(x, W1, W2, Aq, W1q, W2q, statsZ);
  k1_gemm1<<<dim3(8, 128), 256, 0, stream>>>(Aq, W1q, C1, colsum, colsq);
  k45_bnq_gemm2<<<256, 256, 0, stream>>>(C1, colsum, colsq, g1, b1, W2q, C2, sum2p, sq2p);
  k7_bn2q<<<160, 256, 0, stream>>>(C2, sum2p, sq2p, g2, b2, t2, gsum, gsq);
  k9_out<<<NTOT / 256, 256, 0, stream>>>(t2, gsum, gsq, tnw, tnb, (float*)d_out);
}

// Round 7
// 151.770 us; speedup vs baseline: 1.6237x; 1.0003x over previous
//
#include <hip/hip_runtime.h>
#include <stdint.h>

typedef int i32x4 __attribute__((ext_vector_type(4)));
typedef int i32x16 __attribute__((ext_vector_type(16)));
typedef short s16x8 __attribute__((ext_vector_type(8)));
typedef unsigned long long ull;

#define BB 16384
#define KD 784
#define KP 896  // padded to multiple of 128 (BK=128)
#define N1 1024
#define N2 10
#define NTOT (BB * N2)  // 163840

// ---- workspace layout (bytes) ----
#define OFF_AQ 0ULL
#define SZ_AQ (14680064ULL)  // 16384*896 i8
#define OFF_W1Q (OFF_AQ + SZ_AQ)
#define SZ_W1Q (917504ULL)  // 1024*896 i8
#define OFF_W2Q (OFF_W1Q + SZ_W1Q)
#define SZ_W2Q (16384ULL)  // 16*1024 i8 (rows 10..15 poison; masked downstream)
#define OFF_C1 (OFF_W2Q + SZ_W2Q)
#define SZ_C1 (33554432ULL)  // 16384*1024 i16
#define OFF_STATS (OFF_C1 + SZ_C1)
#define SZ_STATS (16384ULL)
// stats sublayout (bytes): colsum int[1024] @0; colsq ull[1024] @4096;
//   sum2p int stride 16 ints (64B), 16 entries @12288;
//   sq2p  ull stride 8 ulls (64B), 16 entries @13312;
//   gsum int @14336; gsq int @14400  (separate cache lines)
#define OFF_C2 (OFF_STATS + SZ_STATS)
#define SZ_C2 (524288ULL)  // 16384*16 i16 (padded cols)
#define OFF_T2 (OFF_C2 + SZ_C2)
#define SZ_T2 (163840ULL)  // i8

__device__ __forceinline__ void async16(const void* g, void* l) {
  __builtin_amdgcn_global_load_lds((__attribute__((address_space(1))) void*)(void*)(g),
                                   (__attribute__((address_space(3))) void*)(l), 16, 0, 0);
}

__device__ __forceinline__ int8_t ternq(float v) {
  float q = rintf(v);
  return q > 0.5f ? 1 : (q < -0.5f ? -1 : 0);
}

// K0: quantize x -> Aq (i8, K padded to 896), W1 -> W1q, W2 -> W2q; zero stats region.
__global__ void k0_quant(const float* __restrict__ x, const float* __restrict__ W1,
                         const float* __restrict__ W2, int8_t* __restrict__ Aq,
                         int8_t* __restrict__ W1q, int8_t* __restrict__ W2q,
                         int* __restrict__ stats) {
  const int TA = BB * KP / 16;  // 917504
  const int TW = N1 * KP / 16;  // 57344
  const int T2 = N2 * N1 / 16;  // 640
  int tid = blockIdx.x * 256 + threadIdx.x;
  if (tid < 4096) stats[tid] = 0;  // 16KB stats zeroed (runs before k1 in stream order)
  union {
    int4 v;
    int8_t b[16];
  } o;
  o.v = make_int4(0, 0, 0, 0);
  if (tid < TA) {
    int base = tid * 16;
    int r = base / KP, k = base - r * KP;
    if (k < KD) {
      const float4* xp = (const float4*)&x[r * KD + k];
#pragma unroll
      for (int g = 0; g < 4; ++g) {
        float4 f = xp[g];
        o.b[g * 4 + 0] = ternq(2.0f * f.x - 1.0f);
        o.b[g * 4 + 1] = ternq(2.0f * f.y - 1.0f);
        o.b[g * 4 + 2] = ternq(2.0f * f.z - 1.0f);
        o.b[g * 4 + 3] = ternq(2.0f * f.w - 1.0f);
      }
    }
    *(int4*)&Aq[base] = o.v;
  } else if (tid < TA + TW) {
    int base = (tid - TA) * 16;
    int r = base / KP, k = base - r * KP;
    if (k < KD) {
      const float4* wp = (const float4*)&W1[r * KD + k];
#pragma unroll
      for (int g = 0; g < 4; ++g) {
        float4 f = wp[g];
        o.b[g * 4 + 0] = ternq(f.x);
        o.b[g * 4 + 1] = ternq(f.y);
        o.b[g * 4 + 2] = ternq(f.z);
        o.b[g * 4 + 3] = ternq(f.w);
      }
    }
    *(int4*)&W1q[base] = o.v;
  } else if (tid < TA + TW + T2) {
    int base = (tid - TA - TW) * 16;
    const float4* wp = (const float4*)&W2[base];
#pragma unroll
    for (int g = 0; g < 4; ++g) {
      float4 f = wp[g];
      o.b[g * 4 + 0] = ternq(f.x);
      o.b[g * 4 + 1] = ternq(f.y);
      o.b[g * 4 + 2] = ternq(f.z);
      o.b[g * 4 + 3] = ternq(f.w);
    }
    *(int4*)&W2q[base] = o.v;
  }
}

// K1: C1 = Aq @ W1q^T (128x128 tile, BK=128, i8 MFMA 32x32x32) + fused col stats.
// 7 K-iters, 16 MFMA/iter (halved inst count vs 16x16x64 at same LDS traffic).
// A/B frag: m=lane&31, k=(lane>>5)*16+j (extension of the verified 16x16x64 map).
// C/D: col=lane&31, row=(reg&3)+8*(reg>>2)+4*(lane>>5)  [HW-verified, dtype-indep].
__global__ __launch_bounds__(256, 4) void k1_gemm1(const int8_t* __restrict__ Aq,
                                                   const int8_t* __restrict__ W1q,
                                                   short* __restrict__ C1,
                                                   int* __restrict__ colsum,
                                                   ull* __restrict__ colsq) {
  __shared__ int8_t As[128 * 128];
  __shared__ int8_t Bs[128 * 128];
  __shared__ int cS[128];
  __shared__ int cQ[128];
  const int t = threadIdx.x;
  const int lane = t & 63, wave = t >> 6;
  const int wr = wave >> 1, wc = wave & 1;
  const int rowBase = blockIdx.y * 128, colBase = blockIdx.x * 128;
  if (t < 128) {
    cS[t] = 0;
    cQ[t] = 0;
  }

  i32x16 acc[2][2] = {};
  const int m32 = lane & 31, kg = lane >> 5;

  // staging: chunk c = t + 256*s, s=0..3; row=c>>3, pos=c&7, granule g = pos ^ (row&7)
  int srow[4], sgo[4];
#pragma unroll
  for (int s = 0; s < 4; ++s) {
    int c = t + 256 * s;
    srow[s] = c >> 3;
    sgo[s] = ((c & 7) ^ (srow[s] & 7)) * 16;
  }

  for (int kt = 0; kt < 7; ++kt) {
    __syncthreads();
    const int kb = kt * 128;
#pragma unroll
    for (int s = 0; s < 4; ++s) {
      int c = t + 256 * s;
      async16(&Aq[(size_t)(rowBase + srow[s]) * KP + kb + sgo[s]], &As[c * 16]);
      async16(&W1q[(size_t)(colBase + srow[s]) * KP + kb + sgo[s]], &Bs[c * 16]);
    }
    __syncthreads();
#pragma unroll
    for (int ks = 0; ks < 4; ++ks) {
      i32x4 av[2], bv[2];
#pragma unroll
      for (int tr = 0; tr < 2; ++tr) {
        int row = 64 * wr + 32 * tr + m32;
        av[tr] = *(const i32x4*)&As[row * 128 + (((ks * 2 + kg) ^ (row & 7)) * 16)];
      }
#pragma unroll
      for (int tc = 0; tc < 2; ++tc) {
        int row = 64 * wc + 32 * tc + m32;
        bv[tc] = *(const i32x4*)&Bs[row * 128 + (((ks * 2 + kg) ^ (row & 7)) * 16)];
      }
#pragma unroll
      for (int tr = 0; tr < 2; ++tr)
#pragma unroll
        for (int tc = 0; tc < 2; ++tc)
          acc[tr][tc] =
              __builtin_amdgcn_mfma_i32_32x32x32_i8(av[tr], bv[tc], acc[tr][tc], 0, 0, 0);
    }
  }

  // epilogue: store C1 (i16) + per-column partial sum/sumsq into LDS
#pragma unroll
  for (int tc = 0; tc < 2; ++tc) {
    const int colLoc = 64 * wc + 32 * tc + m32;
    const int col = colBase + colLoc;
    int s = 0, sq = 0;
#pragma unroll
    for (int tr = 0; tr < 2; ++tr) {
#pragma unroll
      for (int rg = 0; rg < 16; ++rg) {
        int v = acc[tr][tc][rg];
        int row = rowBase + 64 * wr + 32 * tr + (rg & 3) + 8 * (rg >> 2) + 4 * kg;
        C1[(size_t)row * N1 + col] = (short)v;
        s += v;
        sq += v * v;  // <= 128 * 784^2 = 7.9e7, fits int32 per block
      }
    }
    atomicAdd(&cS[colLoc], s);
    atomicAdd(&cQ[colLoc], sq);
  }
  __syncthreads();
  if (t < 128) {
    atomicAdd(&colsum[colBase + t], cS[t]);
    atomicAdd(&colsq[colBase + t], (ull)(unsigned)cQ[t]);
  }
}

// Per-column integer ternary thresholds for z = fma(v,a,b):
// out = (w>=hi) - (w<=lo), w = sgn*v. Exact local search on the fma-evaluated boundary.
__device__ __forceinline__ void mk_thr(double a, double b, int& hi, int& lo, int8_t& sgn) {
  sgn = 1;
  if (a < 0.0) {
    a = -a;
    sgn = -1;  // z = (-v)*(-a) + b : monotone increasing in w=-v
  }
  if (a == 0.0) {
    double q = rint(b);
    if (q > 0.5) {
      hi = -1500;
      lo = -2000;
    } else if (q < -0.5) {
      hi = 2000;
      lo = 1500;
    } else {
      hi = 1500;
      lo = -1500;
    }
    return;
  }
  double g = (0.5 - b) / a;
  g = g > 1e6 ? 1e6 : (g < -1e6 ? -1e6 : g);
  if (g != g) g = 0.0;
  int c0 = (int)floor(g);
  c0 = c0 < -1400 ? -1400 : (c0 > 1400 ? 1400 : c0);
  for (int it = 0; it < 6 && fma((double)(c0 - 1), a, b) > 0.5; ++it) --c0;
  for (int it = 0; it < 6 && fma((double)c0, a, b) <= 0.5; ++it) ++c0;
  hi = c0 < -1500 ? -1500 : (c0 > 1500 ? 1500 : c0);
  double g2 = (-0.5 - b) / a;
  g2 = g2 > 1e6 ? 1e6 : (g2 < -1e6 ? -1e6 : g2);
  if (g2 != g2) g2 = 0.0;
  int c1 = (int)ceil(g2);
  c1 = c1 < -1400 ? -1400 : (c1 > 1400 ? 1400 : c1);
  for (int it = 0; it < 6 && fma((double)(c1 + 1), a, b) < -0.5; ++it) ++c1;
  for (int it = 0; it < 6 && fma((double)c1, a, b) >= -0.5; ++it) --c1;
  lo = c1 < -1500 ? -1500 : (c1 > 1500 ? 1500 : c1);
}

// K45: fused BN1-ternary (integer thresholds) + GEMM2 (i8 MFMA, wave=16x16 tile, K=1024)
// + C2 col stats. Thresholds computed in-block from colsum/colsq.
#define W2S 1040  // LDS row stride for W2 (2-way bank alias = free)
__global__ __launch_bounds__(256) void k45_bnq_gemm2(
    const short* __restrict__ C1, const int* __restrict__ colsum, const ull* __restrict__ colsq,
    const float* __restrict__ g1, const float* __restrict__ b1, const int8_t* __restrict__ W2q,
    short* __restrict__ C2, int* __restrict__ sum2p, ull* __restrict__ sq2p) {
  __shared__ int tpkS[N1];     // (hi<<16) | (lo & 0xffff)
  __shared__ int8_t sgnS[N1];  // per-column sign fold
  __shared__ int8_t W2s[16 * W2S];
  __shared__ int cS[16];
  __shared__ int cQ[16];
  const int t = threadIdx.x;
  for (int i = t; i < N1; i += 256) {
    double mean = (double)colsum[i] / 16384.0;
    double var = (double)colsq[i] / 16384.0 - mean * mean;
    double a = (double)g1[i] / sqrt(var + 1e-5);
    double b = (double)b1[i] - mean * a;
    int hi, lo;
    int8_t sg;
    mk_thr(a, b, hi, lo, sg);
    tpkS[i] = (hi << 16) | (lo & 0xffff);
    sgnS[i] = sg;
  }
  for (int i = t; i < 1024; i += 256) {  // 16KB of W2 as 16B chunks
    int r = i >> 6, c16 = (i & 63) * 16;
    *(int4*)&W2s[r * W2S + c16] = *(const int4*)&W2q[r * N1 + c16];
  }
  if (t < 16) {
    cS[t] = 0;
    cQ[t] = 0;
  }
  __syncthreads();

  const int lane = t & 63, wave = t >> 6;
  const int m = lane & 15, kc = lane >> 4;
  const int tile = blockIdx.x * 4 + wave;  // 0..1023
  const int rowBase = tile * 16;
  const short* arow = &C1[(size_t)(rowBase + m) * N1];

  i32x4 acc = {0, 0, 0, 0};
#pragma unroll
  for (int kt = 0; kt < 16; ++kt) {
    const int k0 = kt * 64 + kc * 16;
    s16x8 v0 = *(const s16x8*)&arow[k0];
    s16x8 v1 = *(const s16x8*)&arow[k0 + 8];
    union {
      int4 v[4];
      int w[16];
    } tps;
    tps.v[0] = *(const int4*)&tpkS[k0];
    tps.v[1] = *(const int4*)&tpkS[k0 + 4];
    tps.v[2] = *(const int4*)&tpkS[k0 + 8];
    tps.v[3] = *(const int4*)&tpkS[k0 + 12];
    union {
      int4 v;
      int8_t b[16];
    } sg;
    sg.v = *(const int4*)&sgnS[k0];
    union {
      i32x4 v;
      int8_t b[16];
    } afr;
#pragma unroll
    for (int j = 0; j < 8; ++j) {
      int tp = tps.w[j];
      int hi = tp >> 16, lo = (short)(tp & 0xffff);
      int w = (int)v0[j] * (int)sg.b[j];
      afr.b[j] = (int8_t)((w >= hi) - (w <= lo));
    }
#pragma unroll
    for (int j = 0; j < 8; ++j) {
      int tp = tps.w[8 + j];
      int hi = tp >> 16, lo = (short)(tp & 0xffff);
      int w = (int)v1[j] * (int)sg.b[8 + j];
      afr.b[8 + j] = (int8_t)((w >= hi) - (w <= lo));
    }
    i32x4 bfr = *(const i32x4*)&W2s[m * W2S + k0];
    acc = __builtin_amdgcn_mfma_i32_16x16x64_i8(afr.v, bfr, acc, 0, 0, 0);
  }

  // C/D layout: col = lane&15, row = (lane>>4)*4 + reg
  const int col = m;
#pragma unroll
  for (int rg = 0; rg < 4; ++rg) C2[(rowBase + kc * 4 + rg) * 16 + col] = (short)acc[rg];
  if (col < N2) {
    int s = 0, sq = 0;
#pragma unroll
    for (int rg = 0; rg < 4; ++rg) {
      int v = acc[rg];
      s += v;
      sq += v * v;
    }
    atomicAdd(&cS[col], s);
    atomicAdd(&cQ[col], sq);
  }
  __syncthreads();
  if (t < N2) {
    atomicAdd(&sum2p[t * 16], cS[t]);
    atomicAdd(&sq2p[t * 8], (ull)(unsigned)cQ[t]);
  }
}

// K7: t2 = ternary(batchnorm2(C2)) + global sum/sumsq of t2 (exact int).
__global__ __launch_bounds__(256) void k7_bn2q(const short* __restrict__ C2,
                                               const int* __restrict__ sum2p,
                                               const ull* __restrict__ sq2p,
                                               const float* __restrict__ g2,
                                               const float* __restrict__ b2,
                                               int8_t* __restrict__ t2, int* __restrict__ gsum,
                                               int* __restrict__ gsq) {
  __shared__ double meanS[N2], rsS[N2];
  if (threadIdx.x < N2) {
    int c = threadIdx.x;
    double mean = (double)sum2p[c * 16] / 16384.0;
    double var = (double)sq2p[c * 8] / 16384.0 - mean * mean;
    meanS[c] = mean;
    rsS[c] = sqrt(var + 1e-5);
  }
  __syncthreads();
  int s = 0, sq = 0;
  for (int id = blockIdx.x * 256 + threadIdx.x; id < NTOT; id += gridDim.x * 256) {
    int r = id / N2, c = id - r * N2;
    int v = C2[r * 16 + c];
    double z = ((double)v - meanS[c]) / rsS[c] * (double)g2[c] + (double)b2[c];
    double qq = rint(z);
    qq = qq < -1.0 ? -1.0 : (qq > 1.0 ? 1.0 : qq);
    int ti = (int)qq;
    t2[id] = (int8_t)ti;
    s += ti;
    sq += ti * ti;
  }
#pragma unroll
  for (int off = 32; off > 0; off >>= 1) {
    s += __shfl_xor(s, off, 64);
    sq += __shfl_xor(sq, off, 64);
  }
  __shared__ int bs, bq;
  if (threadIdx.x == 0) {
    bs = 0;
    bq = 0;
  }
  __syncthreads();
  if ((threadIdx.x & 63) == 0) {
    atomicAdd(&bs, s);
    atomicAdd(&bq, sq);
  }
  __syncthreads();
  if (threadIdx.x == 0) {
    atomicAdd(gsum, bs);
    atomicAdd(gsq, bq);
  }
}

// K9: out = tensornorm(t2)  (unbiased var, eps=1e-4)
__global__ void k9_out(const int8_t* __restrict__ t2, const int* __restrict__ gsum,
                       const int* __restrict__ gsq, const float* __restrict__ tn_w,
                       const float* __restrict__ tn_b, float* __restrict__ out) {
  int id = blockIdx.x * 256 + threadIdx.x;
  double n = (double)NTOT;
  double sm = (double)*gsum;
  double mean = sm / n;
  double var = ((double)*gsq - sm * sm / n) / (n - 1.0);
  double alpha = (double)tn_w[0] / sqrt(var + 1e-4);
  out[id] = (float)(((double)t2[id] - mean) * alpha + (double)tn_b[0]);
}

extern "C" void kernel_launch(void* const* d_in, const int* in_sizes, int n_in, void* d_out,
                              int out_size, void* d_ws, size_t ws_size, hipStream_t stream) {
  const float* x = (const float*)d_in[0];
  const float* W1 = (const float*)d_in[1];
  const float* g1 = (const float*)d_in[2];
  const float* b1 = (const float*)d_in[3];
  const float* W2 = (const float*)d_in[4];
  const float* g2 = (const float*)d_in[5];
  const float* b2 = (const float*)d_in[6];
  const float* tnw = (const float*)d_in[7];
  const float* tnb = (const float*)d_in[8];

  char* ws = (char*)d_ws;
  int8_t* Aq = (int8_t*)(ws + OFF_AQ);
  int8_t* W1q = (int8_t*)(ws + OFF_W1Q);
  int8_t* W2q = (int8_t*)(ws + OFF_W2Q);
  short* C1 = (short*)(ws + OFF_C1);
  int* statsZ = (int*)(ws + OFF_STATS);
  int* colsum = (int*)(ws + OFF_STATS);
  ull* colsq = (ull*)(ws + OFF_STATS + 4096);
  int* sum2p = (int*)(ws + OFF_STATS + 12288);
  ull* sq2p = (ull*)(ws + OFF_STATS + 13312);
  int* gsum = (int*)(ws + OFF_STATS + 14336);
  int* gsq = (int*)(ws + OFF_STATS + 14400);
  short* C2 = (short*)(ws + OFF_C2);
  int8_t* t2 = (int8_t*)(ws + OFF_T2);

  const int totalT = BB * KP / 16 + N1 * KP / 16 + N2 * N1 / 16;  // 975488
  k0_quant<<<(totalT + 255) / 256, 256, 0, stream>>>(x, W1, W2, Aq, W1q, W2q, statsZ);
  k1_gemm1<<<dim3(8, 128), 256, 0, stream>>>(Aq, W1q, C1, colsum, colsq);
  k45_bnq_gemm2<<<256, 256, 0, stream>>>(C1, colsum, colsq, g1, b1, W2q, C2, sum2p, sq2p);
  k7_bn2q<<<160, 256, 0, stream>>>(C2, sum2p, sq2p, g2, b2, t2, gsum, gsq);
  k9_out<<<NTOT / 256, 256, 0, stream>>>(t2, gsum, gsq, tnw, tnb, (float*)d_out);
}